// Round 9
// baseline (319.600 us; speedup 1.0000x reference)
//
#include <hip/hip_runtime.h>

#define Bb 8
#define Nn 1025
#define Hh 12
#define HD 64
#define DIMC 768
#define QKVC 2304          // 3*DIMC, token stride of packed qkv
#define MROWS (Bb * Nn)    // 8200
#define MPADA 8320         // 65*128, padded A rows for unguarded global_load_lds staging
#define VNP 1024           // transposed-V token dim: exactly 8 chunks of 128
#define K1 0.180336880111f // 0.125 * log2(e) — folded into q by rope kernel
#define RBLK ((Bb * Hh * Nn + 3) / 4)   // rope BLOCKS: 98400 waves / 4 per block = 24600
#define VTBLK ((VNP / 64) * Bb * Hh)    // vtrans blocks: 16 * 96 = 1536

typedef _Float16 f16x8 __attribute__((ext_vector_type(8)));
typedef _Float16 f16x4 __attribute__((ext_vector_type(4)));
typedef float f32x4 __attribute__((ext_vector_type(4)));

typedef const __attribute__((address_space(1))) void gv_t;
typedef __attribute__((address_space(3))) void lv_t;

// raw v_exp_f32: skips OCML's denorm-range guard (scores are |s| << 126)
static __device__ __forceinline__ float fast_exp2(float x) {
    return __builtin_amdgcn_exp2f(x);
}

// ---------------- fused fp32 -> fp16 convert for 3 tensors ----------------
__global__ void cvt3_kernel(const float* __restrict__ s0, _Float16* __restrict__ d0, int n0,
                            const float* __restrict__ s1, _Float16* __restrict__ d1, int n1,
                            const float* __restrict__ s2, _Float16* __restrict__ d2, int n2) {
    int i = blockIdx.x * 256 + threadIdx.x;
    const float* s; _Float16* d; int j;
    if (i < n0)           { s = s0; d = d0; j = i; }
    else if (i < n0 + n1) { s = s1; d = d1; j = i - n0; }
    else if (i < n0 + n1 + n2) { s = s2; d = d2; j = i - n0 - n1; }
    else return;
    float4 v = ((const float4*)s)[j];
    f16x4 h;
    h.x = (_Float16)v.x; h.y = (_Float16)v.y; h.z = (_Float16)v.z; h.w = (_Float16)v.w;
    ((f16x4*)d)[j] = h;
}

// ---------------- MFMA GEMM, global_load_lds staging, 2xBK=32 per barrier ----------------
template <int MODE>
__global__ void __launch_bounds__(256) gemm_kernel(
    const _Float16* __restrict__ A, const _Float16* __restrict__ W,
    int M, int Ncols, int K,
    _Float16* __restrict__ outh, const float* __restrict__ bias, float* __restrict__ outf)
{
    __shared__ _Float16 As[2][128 * 32];
    __shared__ _Float16 Ws[2][128 * 32];
    const int tid = threadIdx.x;
    const int wid = tid >> 6, lane = tid & 63;
    const int quad = lane >> 4, l16 = lane & 15;
    const int bm = blockIdx.x * 128, bn = blockIdx.y * 128;
    const int wm = (wid >> 1) * 64, wn = (wid & 1) * 64;

    f32x4 acc[4][4] = {};

    for (int kk = 0; kk < K; kk += 64) {
#pragma unroll
        for (int half = 0; half < 2; ++half) {
#pragma unroll
            for (int c = 0; c < 2; ++c) {
                int s = c * 256 + tid;
                int row = s >> 2, gr = s & 3;
                const _Float16* ga = A + (size_t)(bm + row) * K + kk + half * 32 + gr * 8;
                const _Float16* gw = W + (size_t)(bn + row) * K + kk + half * 32 + gr * 8;
                _Float16* la = As[half] + (size_t)(c * 256 + wid * 64) * 8;
                _Float16* lw = Ws[half] + (size_t)(c * 256 + wid * 64) * 8;
                __builtin_amdgcn_global_load_lds((gv_t*)ga, (lv_t*)la, 16, 0, 0);
                __builtin_amdgcn_global_load_lds((gv_t*)gw, (lv_t*)lw, 16, 0, 0);
            }
        }
        __syncthreads();

#pragma unroll
        for (int half = 0; half < 2; ++half) {
            f16x8 af[4], bf[4];
#pragma unroll
            for (int t = 0; t < 4; ++t) {
                af[t] = *(const f16x8*)(As[half] + (size_t)(wm + t * 16 + l16) * 32 + quad * 8);
                bf[t] = *(const f16x8*)(Ws[half] + (size_t)(wn + t * 16 + l16) * 32 + quad * 8);
            }
#pragma unroll
            for (int tm = 0; tm < 4; ++tm)
#pragma unroll
                for (int tn = 0; tn < 4; ++tn)
                    acc[tm][tn] = __builtin_amdgcn_mfma_f32_16x16x32_f16(af[tm], bf[tn], acc[tm][tn], 0, 0, 0);
        }
        __syncthreads();
    }

#pragma unroll
    for (int tm = 0; tm < 4; ++tm) {
#pragma unroll
        for (int r = 0; r < 4; ++r) {
            int row = bm + wm + tm * 16 + quad * 4 + r;
            if (row >= M) continue;
#pragma unroll
            for (int tn = 0; tn < 4; ++tn) {
                int col = bn + wn + tn * 16 + l16;
                float val = acc[tm][tn][r];
                if (MODE == 0) {
                    outh[(size_t)row * Ncols + col] = (_Float16)val;
                } else {
                    outf[(size_t)row * Ncols + col] = val + bias[col];
                }
            }
        }
    }
}

// ---------------- fused RoPE-2D (+scale-fold, cls dots) and V-transpose ----------------
__global__ void __launch_bounds__(256) ropevtrans_kernel(
    _Float16* __restrict__ qkv, const int* __restrict__ xpos,
    float* __restrict__ col0, float* __restrict__ row0, _Float16* __restrict__ vt)
{
    __shared__ _Float16 Ts[64][72];
    const int blk = blockIdx.x;
    const int tid = threadIdx.x;

    if (blk < RBLK) {
        // ---- rope part: one wave per (b,h,n) ----
        int gw = blk * 4 + (tid >> 6);
        int lane = tid & 63;
        if (gw >= Bb * Hh * Nn) return;
        int n = gw % Nn;
        int bh = gw / Nn;
        int b = bh / Hh, h = bh - b * Hh;

        _Float16* qp = qkv + ((size_t)b * Nn + n) * QKVC + h * HD;
        _Float16* kp = qp + DIMC;
        const _Float16* qp0 = qkv + (size_t)b * Nn * QKVC + h * HD;
        const _Float16* kp0 = qp0 + DIMC;

        float q = (float)qp[lane];
        float k = (float)kp[lane];
        float q0 = (float)qp0[lane];
        float k0 = (float)kp0[lane];

        float dcol = q * k0, drow = q0 * k;
#pragma unroll
        for (int off = 1; off < 64; off <<= 1) {
            dcol += __shfl_xor(dcol, off);
            drow += __shfl_xor(drow, off);
        }
        if (lane == 0) {
            col0[gw] = dcol * K1;   // pre-scaled: flash does p = exp2(value)
            row0[gw] = drow * K1;
        }

        if (n >= 1) {
            int py = xpos[((size_t)b * Nn + n) * 2 + 0];
            int px = xpos[((size_t)b * Nn + n) * 2 + 1];
            float pos = (lane < 32) ? (float)py : (float)px;
            int j = lane & 15;
            float inv = __expf(-0.28782313662f * (float)j);   // 100^(-j/16)
            float ang = pos * inv;
            float sv = __sinf(ang), cv = __cosf(ang);
            float qp_ = __shfl_xor(q, 16);
            float kp_ = __shfl_xor(k, 16);
            float sgn = (lane & 16) ? 1.0f : -1.0f;
            qp[lane] = (_Float16)((q * cv + sgn * qp_ * sv) * K1);   // scale folded into q
            kp[lane] = (_Float16)(k * cv + sgn * kp_ * sv);          // k unscaled
        }
    } else {
        // ---- vtrans part: qkv v-slice (tokens 0..1023) -> vt[bh][64][VNP] ----
        int idx = blk - RBLK;
        int nt = idx % (VNP / 64);
        int bh = idx / (VNP / 64);
        int b = bh / Hh, h = bh - b * Hh;
        int n0 = nt * 64;
        const _Float16* vsrc = qkv + (size_t)b * Nn * QKVC + 2 * DIMC + h * HD;
#pragma unroll
        for (int i = 0; i < 2; ++i) {
            int t = tid + i * 256;
            int r = t >> 3, cg = t & 7;
            f16x8 v8 = *(const f16x8*)(vsrc + (size_t)(n0 + r) * QKVC + cg * 8);
            *(f16x8*)&Ts[r][cg * 8] = v8;
        }
        __syncthreads();
#pragma unroll
        for (int i = 0; i < 2; ++i) {
            int t = tid + i * 256;
            int d = t >> 3, ng = t & 7;
            f16x8 o;
#pragma unroll
            for (int s = 0; s < 8; ++s) o[s] = Ts[ng * 8 + s][d];
            *(f16x8*)(vt + ((size_t)bh * HD + d) * VNP + n0 + ng * 8) = o;
        }
    }
}

// ---------------- flash attention R19: R18 + LDS pads retuned for 3 blocks/CU ----------------
// R18 post-mortem: per-output LDS work halved (conflicts 7.57M->4.48M) but LDS 54.3KB
// missed the 3-blocks/CU cut (3x54272=162816 vs 163840 budget minus runtime reserve)
// -> occupancy 25->16% cancelled the gain; dur pinned at 77.0. R19 changes ONLY the
// three pad constants: Ks/Ps [72]->[68], Vt [136]->[132]. Total 51712B -> 3 blocks/CU
// with margin. Bank math at stride 68 halves (34 words == 2 mod 32): Ps b16 writes'
// quad offset = 136 == 8 mod 32 -> quads hit banks {0,8,16,24}+l16/2 = all 32 banks,
// 2 lanes/bank (free; was 4-way). bk/bv/ap b128 reads: start word (2*l16+4*quad)%32
// -> 4 lanes per 4-word window (was 8) ~ at the 8-access/bank floor.
__global__ void __launch_bounds__(256) flash_kernel(
    const _Float16* __restrict__ qkv, const _Float16* __restrict__ vt,
    const float* __restrict__ col0, const float* __restrict__ row0,
    _Float16* __restrict__ att)
{
    __shared__ _Float16 Ks[128][68];
    __shared__ _Float16 Vt[64][132];
    __shared__ _Float16 Ps[128][68];   // wave-private rows, 64 k-cols per sub-step

    const int qt = blockIdx.x, bh = blockIdx.y;
    const int b = bh / Hh, h = bh - b * Hh;
    const int tid = threadIdx.x, wid = tid >> 6, lane = tid & 63;
    const int quad = lane >> 4, l16 = lane & 15;
    const int q0row = qt * 128;
    const int c0base = bh * Nn;
    const _Float16* qg = qkv + (size_t)b * Nn * QKVC + h * HD;   // + n*QKVC + d
    const _Float16* kg = qg + DIMC;
    const _Float16* vtg = vt + (size_t)bh * HD * VNP;

    // staging coordinates (fixed per thread)
    const int kR = tid >> 3, kC = (tid & 7) * 8;    // K: rows kR + i*32
    const int vD = tid >> 4, vC = (tid & 15) * 8;   // V: rows vD + i*16

    // stage 128 Q rows into Ks, hoist both halves' fragments, release the buffer
#pragma unroll
    for (int i = 0; i < 4; ++i) {
        int t = tid + i * 256;
        int r = t >> 3, cg = t & 7;
        int gr = q0row + r;
        f16x8 v8 = {};
        if (gr < Nn) v8 = *(const f16x8*)(qg + (size_t)gr * QKVC + cg * 8);
        *(f16x8*)&Ks[r][cg * 8] = v8;
    }
    __syncthreads();
    f16x8 aq[2][2];
#pragma unroll
    for (int q2 = 0; q2 < 2; ++q2)
#pragma unroll
        for (int ks = 0; ks < 2; ++ks)
            aq[q2][ks] = *(const f16x8*)&Ks[q2 * 64 + wid * 16 + l16][ks * 32 + quad * 8];
    __syncthreads();

    f32x4 oacc[2][4] = {};                       // [q2][ct]
    float lrow[2][4] = {{0.f,0.f,0.f,0.f},{0.f,0.f,0.f,0.f}};

    // prefetch chunk 0 into registers (rows 0..127 all valid -> no guards)
    f16x8 kreg[4], vreg[4];
#pragma unroll
    for (int i = 0; i < 4; ++i) {
        kreg[i] = *(const f16x8*)(kg + (size_t)(kR + i * 32) * QKVC + kC);
        vreg[i] = *(const f16x8*)(vtg + (size_t)(vD + i * 16) * VNP + vC);
    }

    for (int c0 = 0; c0 < VNP; c0 += 128) {
        // commit prefetched registers to LDS
#pragma unroll
        for (int i = 0; i < 4; ++i) {
            *(f16x8*)&Ks[kR + i * 32][kC] = kreg[i];
            *(f16x8*)&Vt[vD + i * 16][vC] = vreg[i];
        }
        __syncthreads();

        // prefetch next chunk (rows <= 1023, unguarded; overlapped with compute)
        int cn = c0 + 128;
        if (cn < VNP) {
#pragma unroll
            for (int i = 0; i < 4; ++i) {
                kreg[i] = *(const f16x8*)(kg + (size_t)(cn + kR + i * 32) * QKVC + kC);
                vreg[i] = *(const f16x8*)(vtg + (size_t)(vD + i * 16) * VNP + cn + vC);
            }
        }

        // two 64-col sub-steps; sacc[2][4] reused (keeps VGPR at R16 level)
#pragma unroll
        for (int sub = 0; sub < 2; ++sub) {
            // S' = Q' K^T for both q-halves; each bk feeds 2 MFMAs
            f32x4 sacc[2][4] = {};
#pragma unroll
            for (int ks = 0; ks < 2; ++ks)
#pragma unroll
                for (int ct = 0; ct < 4; ++ct) {
                    f16x8 bk = *(const f16x8*)&Ks[sub * 64 + ct * 16 + l16][ks * 32 + quad * 8];
                    sacc[0][ct] = __builtin_amdgcn_mfma_f32_16x16x32_f16(aq[0][ks], bk, sacc[0][ct], 0, 0, 0);
                    sacc[1][ct] = __builtin_amdgcn_mfma_f32_16x16x32_f16(aq[1][ks], bk, sacc[1][ct], 0, 0, 0);
                }

            // cls column (k==0): chunk 0, sub 0, col l16==0
            if (c0 == 0 && sub == 0 && l16 == 0) {
#pragma unroll
                for (int q2 = 0; q2 < 2; ++q2)
#pragma unroll
                    for (int r = 0; r < 4; ++r) {
                        int gi = q0row + q2 * 64 + wid * 16 + quad * 4 + r;
                        sacc[q2][0][r] = col0[c0base + (gi < Nn ? gi : 0)];
                    }
            }
            // cls row (q==0): block 0, half 0, wave 0, quad 0 (row r==0)
            if (q0row == 0 && wid == 0 && quad == 0) {
#pragma unroll
                for (int ct = 0; ct < 4; ++ct)
                    sacc[0][ct][0] = row0[c0base + c0 + sub * 64 + ct * 16 + l16];
            }

            // p = 2^s'; partial row sums; stage to Ps (f16, 64-wide)
#pragma unroll
            for (int q2 = 0; q2 < 2; ++q2)
#pragma unroll
                for (int ct = 0; ct < 4; ++ct) {
#pragma unroll
                    for (int r = 0; r < 4; ++r) {
                        float p = fast_exp2(sacc[q2][ct][r]);
                        lrow[q2][r] += p;
                        Ps[q2 * 64 + wid * 16 + quad * 4 + r][ct * 16 + l16] = (_Float16)p;
                    }
                }

            // O += P @ V over this sub-step's 64 k-cols; each bv feeds 2 MFMAs
#pragma unroll
            for (int ks = 0; ks < 2; ++ks) {
                f16x8 ap0 = *(const f16x8*)&Ps[wid * 16 + l16][ks * 32 + quad * 8];
                f16x8 ap1 = *(const f16x8*)&Ps[64 + wid * 16 + l16][ks * 32 + quad * 8];
                int kglob = sub * 2 + ks;
#pragma unroll
                for (int ct = 0; ct < 4; ++ct) {
                    f16x8 bv = *(const f16x8*)&Vt[ct * 16 + l16][kglob * 32 + quad * 8];
                    oacc[0][ct] = __builtin_amdgcn_mfma_f32_16x16x32_f16(ap0, bv, oacc[0][ct], 0, 0, 0);
                    oacc[1][ct] = __builtin_amdgcn_mfma_f32_16x16x32_f16(ap1, bv, oacc[1][ct], 0, 0, 0);
                }
            }
        }
        __syncthreads();   // Ks/Vt consumed before next chunk's commit
    }

    // ---- per-half epilogue: token-1024 rank-1, l-reduce, store ----
    const _Float16* k1 = kg + (size_t)1024 * QKVC;
    f16x8 kk0 = *(const f16x8*)(k1 + quad * 8);
    f16x8 kk1 = *(const f16x8*)(k1 + 32 + quad * 8);
    const _Float16* v1 = qg + 2 * DIMC + (size_t)1024 * QKVC;
    float vv[4];
#pragma unroll
    for (int ct = 0; ct < 4; ++ct) vv[ct] = (float)v1[ct * 16 + l16];

#pragma unroll
    for (int q2 = 0; q2 < 2; ++q2) {
        float part = 0.f;
#pragma unroll
        for (int j = 0; j < 8; ++j)
            part += (float)aq[q2][0][j] * (float)kk0[j] + (float)aq[q2][1][j] * (float)kk1[j];
        part += __shfl_xor(part, 16);
        part += __shfl_xor(part, 32);   // s' for Q row q2*64 + wid*16 + l16 (replicated)
        float s = part;
        if (q0row == 0 && q2 == 0 && wid == 0 && l16 == 0) s = row0[c0base + 1024];  // cls row
        float p = fast_exp2(s);
        // add p for row l16 into its owning lrow slot: lane with quad == l16>>2, r == l16&3
#pragma unroll
        for (int r = 0; r < 4; ++r)
            if (quad == (l16 >> 2) && (l16 & 3) == r) lrow[q2][r] += p;
        // O rank-1 update: p_r for row ..+quad*4+r lives in lane (quad*4 + r)
#pragma unroll
        for (int r = 0; r < 4; ++r) {
            float pr = __shfl(p, quad * 4 + r);
#pragma unroll
            for (int ct = 0; ct < 4; ++ct) oacc[q2][ct][r] += pr * vv[ct];
        }

        // l-reduce over l16 groups + store
#pragma unroll
        for (int r = 0; r < 4; ++r) {
            float l = lrow[q2][r];
#pragma unroll
            for (int off = 1; off < 16; off <<= 1) l += __shfl_xor(l, off);
            int gi = q0row + q2 * 64 + wid * 16 + quad * 4 + r;
            if (gi >= Nn) continue;
            float inv_l = 1.0f / l;
#pragma unroll
            for (int ct = 0; ct < 4; ++ct) {
                att[((size_t)b * Nn + gi) * DIMC + h * HD + ct * 16 + l16] =
                    (_Float16)(oacc[q2][ct][r] * inv_l);
            }
        }
    }
}

extern "C" void kernel_launch(void* const* d_in, const int* in_sizes, int n_in,
                              void* d_out, int out_size, void* d_ws, size_t ws_size,
                              hipStream_t stream) {
    const float* x      = (const float*)d_in[1];
    const int*   xpos   = (const int*)d_in[2];
    const float* w_qkv  = (const float*)d_in[4];
    const float* w_proj = (const float*)d_in[5];
    const float* b_proj = (const float*)d_in[6];
    float* out = (float*)d_out;

    char* ws = (char*)d_ws;
    size_t off = 0;
    auto alloc = [&](size_t bytes) {
        char* p = ws + off;
        off += (bytes + 255) & ~(size_t)255;
        return p;
    };
    _Float16* xh     = (_Float16*)alloc((size_t)MPADA * DIMC * 2);   // padded rows for unguarded staging
    _Float16* qkvh   = (_Float16*)alloc((size_t)MROWS * QKVC * 2);
    _Float16* vt     = (_Float16*)alloc((size_t)Bb * Hh * HD * VNP * 2);
    _Float16* wqkvh  = (_Float16*)alloc((size_t)3 * DIMC * DIMC * 2);
    _Float16* wprojh = (_Float16*)alloc((size_t)DIMC * DIMC * 2);
    float* col0      = (float*)alloc((size_t)Bb * Hh * Nn * 4);
    float* row0      = (float*)alloc((size_t)Bb * Hh * Nn * 4);
    _Float16* atth   = xh;  // alias: x consumed by QKV GEMM before flash writes att

    {
        int n0 = (MROWS * DIMC) / 4;
        int n1 = (3 * DIMC * DIMC) / 4;
        int n2 = (DIMC * DIMC) / 4;
        int nt = n0 + n1 + n2;
        cvt3_kernel<<<(nt + 255) / 256, 256, 0, stream>>>(
            x, xh, n0, w_qkv, wqkvh, n1, w_proj, wprojh, n2);
    }

    // QKV projection -> packed [b,n,3,h,d] (natural GEMM C layout)
    gemm_kernel<0><<<dim3(MPADA / 128, QKVC / 128), 256, 0, stream>>>(
        xh, wqkvh, MROWS, QKVC, DIMC, qkvh, nullptr, nullptr);

    // fused rope (q/k) + V transpose (tokens 0..1023)
    ropevtrans_kernel<<<RBLK + VTBLK, 256, 0, stream>>>(
        qkvh, xpos, col0, row0, vt);

    flash_kernel<<<dim3((Nn + 127) / 128, Bb * Hh), 256, 0, stream>>>(
        qkvh, vt, col0, row0, atth);

    gemm_kernel<1><<<dim3(MPADA / 128, DIMC / 128), 256, 0, stream>>>(
        atth, wprojh, MROWS, DIMC, DIMC, nullptr, b_proj, out);
}

// Round 10
// 284.930 us; speedup vs baseline: 1.1217x; 1.1217x over previous
//
#include <hip/hip_runtime.h>

#define Bb 8
#define Nn 1025
#define Hh 12
#define HD 64
#define DIMC 768
#define QKVC 2304          // 3*DIMC, token stride of packed qkv
#define MROWS (Bb * Nn)    // 8200
#define MPADA 8320         // 65*128, padded A rows for unguarded global_load_lds staging
#define VNP 1024           // transposed-V token dim: exactly 8 chunks of 128
#define K1 0.180336880111f // 0.125 * log2(e) — folded into q by rope kernel
#define RBLK ((Bb * Hh * Nn + 3) / 4)   // rope BLOCKS: 98400 waves / 4 per block = 24600
#define VTBLK ((VNP / 64) * Bb * Hh)    // vtrans blocks: 16 * 96 = 1536

typedef _Float16 f16x8 __attribute__((ext_vector_type(8)));
typedef _Float16 f16x4 __attribute__((ext_vector_type(4)));
typedef float f32x4 __attribute__((ext_vector_type(4)));

typedef const __attribute__((address_space(1))) void gv_t;
typedef __attribute__((address_space(3))) void lv_t;

// raw v_exp_f32: skips OCML's denorm-range guard (scores are |s| << 126)
static __device__ __forceinline__ float fast_exp2(float x) {
    return __builtin_amdgcn_exp2f(x);
}

// ---------------- fused fp32 -> fp16 convert for 3 tensors + rope trig table ----------------
// xpos in [0,32), j in [0,16): only 512 distinct (cos,sin) pairs. Tail threads build
// tab[p*16+j] = (cos(p*100^(-j/16)), sin(...)) with the SAME intrinsics the rope
// kernel used -> bit-identical results, ~100 VALU cycles of trig per rope lane -> 1 load.
__global__ void cvt3_kernel(const float* __restrict__ s0, _Float16* __restrict__ d0, int n0,
                            const float* __restrict__ s1, _Float16* __restrict__ d1, int n1,
                            const float* __restrict__ s2, _Float16* __restrict__ d2, int n2,
                            float2* __restrict__ tab) {
    int i = blockIdx.x * 256 + threadIdx.x;
    int nt = n0 + n1 + n2;
    if (i >= nt) {
        int t = i - nt;
        if (t < 512) {
            int p = t >> 4, j = t & 15;
            float ang = (float)p * __expf(-0.28782313662f * (float)j);   // 100^(-j/16)
            tab[t] = make_float2(__cosf(ang), __sinf(ang));
        }
        return;
    }
    const float* s; _Float16* d; int j;
    if (i < n0)           { s = s0; d = d0; j = i; }
    else if (i < n0 + n1) { s = s1; d = d1; j = i - n0; }
    else                  { s = s2; d = d2; j = i - n0 - n1; }
    float4 v = ((const float4*)s)[j];
    f16x4 h;
    h.x = (_Float16)v.x; h.y = (_Float16)v.y; h.z = (_Float16)v.z; h.w = (_Float16)v.w;
    ((f16x4*)d)[j] = h;
}

// ---------------- MFMA GEMM, global_load_lds staging, 2xBK=32 per barrier ----------------
template <int MODE>
__global__ void __launch_bounds__(256) gemm_kernel(
    const _Float16* __restrict__ A, const _Float16* __restrict__ W,
    int M, int Ncols, int K,
    _Float16* __restrict__ outh, const float* __restrict__ bias, float* __restrict__ outf)
{
    __shared__ _Float16 As[2][128 * 32];
    __shared__ _Float16 Ws[2][128 * 32];
    const int tid = threadIdx.x;
    const int wid = tid >> 6, lane = tid & 63;
    const int quad = lane >> 4, l16 = lane & 15;
    const int bm = blockIdx.x * 128, bn = blockIdx.y * 128;
    const int wm = (wid >> 1) * 64, wn = (wid & 1) * 64;

    f32x4 acc[4][4] = {};

    for (int kk = 0; kk < K; kk += 64) {
#pragma unroll
        for (int half = 0; half < 2; ++half) {
#pragma unroll
            for (int c = 0; c < 2; ++c) {
                int s = c * 256 + tid;
                int row = s >> 2, gr = s & 3;
                const _Float16* ga = A + (size_t)(bm + row) * K + kk + half * 32 + gr * 8;
                const _Float16* gw = W + (size_t)(bn + row) * K + kk + half * 32 + gr * 8;
                _Float16* la = As[half] + (size_t)(c * 256 + wid * 64) * 8;
                _Float16* lw = Ws[half] + (size_t)(c * 256 + wid * 64) * 8;
                __builtin_amdgcn_global_load_lds((gv_t*)ga, (lv_t*)la, 16, 0, 0);
                __builtin_amdgcn_global_load_lds((gv_t*)gw, (lv_t*)lw, 16, 0, 0);
            }
        }
        __syncthreads();

#pragma unroll
        for (int half = 0; half < 2; ++half) {
            f16x8 af[4], bf[4];
#pragma unroll
            for (int t = 0; t < 4; ++t) {
                af[t] = *(const f16x8*)(As[half] + (size_t)(wm + t * 16 + l16) * 32 + quad * 8);
                bf[t] = *(const f16x8*)(Ws[half] + (size_t)(wn + t * 16 + l16) * 32 + quad * 8);
            }
#pragma unroll
            for (int tm = 0; tm < 4; ++tm)
#pragma unroll
                for (int tn = 0; tn < 4; ++tn)
                    acc[tm][tn] = __builtin_amdgcn_mfma_f32_16x16x32_f16(af[tm], bf[tn], acc[tm][tn], 0, 0, 0);
        }
        __syncthreads();
    }

#pragma unroll
    for (int tm = 0; tm < 4; ++tm) {
#pragma unroll
        for (int r = 0; r < 4; ++r) {
            int row = bm + wm + tm * 16 + quad * 4 + r;
            if (row >= M) continue;
#pragma unroll
            for (int tn = 0; tn < 4; ++tn) {
                int col = bn + wn + tn * 16 + l16;
                float val = acc[tm][tn][r];
                if (MODE == 0) {
                    outh[(size_t)row * Ncols + col] = (_Float16)val;
                } else {
                    outf[(size_t)row * Ncols + col] = val + bias[col];
                }
            }
        }
    }
}

// ---------------- fused RoPE-2D (+scale-fold, cls dots) and V-transpose ----------------
__global__ void __launch_bounds__(256) ropevtrans_kernel(
    _Float16* __restrict__ qkv, const int* __restrict__ xpos,
    float* __restrict__ col0, float* __restrict__ row0, _Float16* __restrict__ vt,
    const float2* __restrict__ tab)
{
    __shared__ _Float16 Ts[64][72];
    const int blk = blockIdx.x;
    const int tid = threadIdx.x;

    if (blk < RBLK) {
        // ---- rope part: one wave per (b,h,n) ----
        int gw = blk * 4 + (tid >> 6);
        int lane = tid & 63;
        if (gw >= Bb * Hh * Nn) return;
        int n = gw % Nn;
        int bh = gw / Nn;
        int b = bh / Hh, h = bh - b * Hh;

        _Float16* qp = qkv + ((size_t)b * Nn + n) * QKVC + h * HD;
        _Float16* kp = qp + DIMC;
        const _Float16* qp0 = qkv + (size_t)b * Nn * QKVC + h * HD;
        const _Float16* kp0 = qp0 + DIMC;

        float q = (float)qp[lane];
        float k = (float)kp[lane];
        float q0 = (float)qp0[lane];
        float k0 = (float)kp0[lane];

        float dcol = q * k0, drow = q0 * k;
#pragma unroll
        for (int off = 1; off < 64; off <<= 1) {
            dcol += __shfl_xor(dcol, off);
            drow += __shfl_xor(drow, off);
        }
        if (lane == 0) {
            col0[gw] = dcol * K1;   // pre-scaled: flash does p = exp2(value)
            row0[gw] = drow * K1;
        }

        if (n >= 1) {
            int py = xpos[((size_t)b * Nn + n) * 2 + 0];
            int px = xpos[((size_t)b * Nn + n) * 2 + 1];
            int pos = (lane < 32) ? py : px;
            int j = lane & 15;
            float2 cs = tab[((pos & 31) << 4) | j];   // (cos, sin) of pos*100^(-j/16)
            float cv = cs.x, sv = cs.y;
            float qp_ = __shfl_xor(q, 16);
            float kp_ = __shfl_xor(k, 16);
            float sgn = (lane & 16) ? 1.0f : -1.0f;
            qp[lane] = (_Float16)((q * cv + sgn * qp_ * sv) * K1);   // scale folded into q
            kp[lane] = (_Float16)(k * cv + sgn * kp_ * sv);          // k unscaled
        }
    } else {
        // ---- vtrans part: qkv v-slice (tokens 0..1023) -> vt[bh][64][VNP] ----
        int idx = blk - RBLK;
        int nt = idx % (VNP / 64);
        int bh = idx / (VNP / 64);
        int b = bh / Hh, h = bh - b * Hh;
        int n0 = nt * 64;
        const _Float16* vsrc = qkv + (size_t)b * Nn * QKVC + 2 * DIMC + h * HD;
#pragma unroll
        for (int i = 0; i < 2; ++i) {
            int t = tid + i * 256;
            int r = t >> 3, cg = t & 7;
            f16x8 v8 = *(const f16x8*)(vsrc + (size_t)(n0 + r) * QKVC + cg * 8);
            *(f16x8*)&Ts[r][cg * 8] = v8;
        }
        __syncthreads();
#pragma unroll
        for (int i = 0; i < 2; ++i) {
            int t = tid + i * 256;
            int d = t >> 3, ng = t & 7;
            f16x8 o;
#pragma unroll
            for (int s = 0; s < 8; ++s) o[s] = Ts[ng * 8 + s][d];
            *(f16x8*)(vt + ((size_t)bh * HD + d) * VNP + n0 + ng * 8) = o;
        }
    }
}

// ---------------- flash attention: R16 verbatim (best measured: 77.0 us) ----------------
// R19 lesson: LDS row stride must be a multiple of 8 halves (16B) or b128 LDS ops
// split (68/132 pads -> +35us). R16/R18 both measure 77.0; flash is balanced
// (LDS ~30%, VALU ~30%, latency) with no dominant term -> frozen at the R16 form
// (lowest VGPR=80, occ 25%). Ps staging, fast_exp2, rank-1 token-1024 epilogue.
__global__ void __launch_bounds__(256) flash_kernel(
    const _Float16* __restrict__ qkv, const _Float16* __restrict__ vt,
    const float* __restrict__ col0, const float* __restrict__ row0,
    _Float16* __restrict__ att)
{
    __shared__ _Float16 Ks[128][72];
    __shared__ _Float16 Vt[64][136];
    __shared__ _Float16 Ps[64][136];   // wave-private rows

    const int qt = blockIdx.x, bh = blockIdx.y;
    const int b = bh / Hh, h = bh - b * Hh;
    const int tid = threadIdx.x, wid = tid >> 6, lane = tid & 63;
    const int quad = lane >> 4, l16 = lane & 15;
    const int q0row = qt * 64;
    const int c0base = bh * Nn;
    const _Float16* qg = qkv + (size_t)b * Nn * QKVC + h * HD;   // + n*QKVC + d
    const _Float16* kg = qg + DIMC;
    const _Float16* vtg = vt + (size_t)bh * HD * VNP;

    // staging coordinates (fixed per thread)
    const int kR = tid >> 3, kC = (tid & 7) * 8;    // K: rows kR + i*32
    const int vD = tid >> 4, vC = (tid & 15) * 8;   // V: rows vD + i*16

    // stage Q tile into Ks rows 0..63, hoist fragments, release the buffer
#pragma unroll
    for (int i = 0; i < 2; ++i) {
        int t = tid + i * 256;
        int r = t >> 3, cg = t & 7;
        int gr = q0row + r;
        f16x8 v8 = {};
        if (gr < Nn) v8 = *(const f16x8*)(qg + (size_t)gr * QKVC + cg * 8);
        *(f16x8*)&Ks[r][cg * 8] = v8;
    }
    __syncthreads();
    f16x8 aq[2];
#pragma unroll
    for (int ks = 0; ks < 2; ++ks)
        aq[ks] = *(const f16x8*)&Ks[wid * 16 + l16][ks * 32 + quad * 8];
    __syncthreads();

    f32x4 oacc[4] = {};
    float lrow[4] = {0.f, 0.f, 0.f, 0.f};
    const int gibase = q0row + wid * 16 + quad * 4;

    // prefetch chunk 0 into registers (rows 0..127 all valid -> no guards)
    f16x8 kreg[4], vreg[4];
#pragma unroll
    for (int i = 0; i < 4; ++i) {
        kreg[i] = *(const f16x8*)(kg + (size_t)(kR + i * 32) * QKVC + kC);
        vreg[i] = *(const f16x8*)(vtg + (size_t)(vD + i * 16) * VNP + vC);
    }

    for (int c0 = 0; c0 < VNP; c0 += 128) {
        // commit prefetched registers to LDS
#pragma unroll
        for (int i = 0; i < 4; ++i) {
            *(f16x8*)&Ks[kR + i * 32][kC] = kreg[i];
            *(f16x8*)&Vt[vD + i * 16][vC] = vreg[i];
        }
        __syncthreads();

        // prefetch next chunk (rows <= 1023, unguarded; overlapped with compute)
        int cn = c0 + 128;
        if (cn < VNP) {
#pragma unroll
            for (int i = 0; i < 4; ++i) {
                kreg[i] = *(const f16x8*)(kg + (size_t)(cn + kR + i * 32) * QKVC + kC);
                vreg[i] = *(const f16x8*)(vtg + (size_t)(vD + i * 16) * VNP + cn + vC);
            }
        }

        // S' = Q' K^T  (scale already folded into Q)
        f32x4 sacc[8] = {};
#pragma unroll
        for (int ks = 0; ks < 2; ++ks)
#pragma unroll
            for (int ct = 0; ct < 8; ++ct) {
                f16x8 bk = *(const f16x8*)&Ks[ct * 16 + l16][ks * 32 + quad * 8];
                sacc[ct] = __builtin_amdgcn_mfma_f32_16x16x32_f16(aq[ks], bk, sacc[ct], 0, 0, 0);
            }

        // cls column (gj==0): only chunk 0
        if (c0 == 0 && l16 == 0) {
#pragma unroll
            for (int r = 0; r < 4; ++r) {
                int gi = gibase + r;
                sacc[0][r] = col0[c0base + (gi < Nn ? gi : 0)];
            }
        }
        // cls row (gi==0): only first q-tile, wave 0, quad 0
        if (q0row == 0 && wid == 0 && quad == 0) {
#pragma unroll
            for (int ct = 0; ct < 8; ++ct)
                sacc[ct][0] = row0[c0base + c0 + ct * 16 + l16];
        }

        // p = 2^s'; partial row sums; stage to Ps (f16)
#pragma unroll
        for (int ct = 0; ct < 8; ++ct) {
#pragma unroll
            for (int r = 0; r < 4; ++r) {
                float p = fast_exp2(sacc[ct][r]);
                lrow[r] += p;
                Ps[wid * 16 + quad * 4 + r][ct * 16 + l16] = (_Float16)p;
            }
        }

        // O += P @ V  (own Ps rows + shared Vt, all from LDS)
#pragma unroll
        for (int ks = 0; ks < 4; ++ks) {
            f16x8 ap = *(const f16x8*)&Ps[wid * 16 + l16][ks * 32 + quad * 8];
#pragma unroll
            for (int ct = 0; ct < 4; ++ct) {
                f16x8 bv = *(const f16x8*)&Vt[ct * 16 + l16][ks * 32 + quad * 8];
                oacc[ct] = __builtin_amdgcn_mfma_f32_16x16x32_f16(ap, bv, oacc[ct], 0, 0, 0);
            }
        }
        __syncthreads();   // Ks/Vt consumed before next chunk's commit
    }

    // ---- token 1024: rank-1 contribution outside the chunk loop ----
    {
        const _Float16* k1 = kg + (size_t)1024 * QKVC;
        f16x8 kk0 = *(const f16x8*)(k1 + quad * 8);
        f16x8 kk1 = *(const f16x8*)(k1 + 32 + quad * 8);
        float part = 0.f;
#pragma unroll
        for (int j = 0; j < 8; ++j)
            part += (float)aq[0][j] * (float)kk0[j] + (float)aq[1][j] * (float)kk1[j];
        part += __shfl_xor(part, 16);
        part += __shfl_xor(part, 32);   // s' for Q row wid*16 + l16 (replicated over quads)
        float s = part;
        if (q0row == 0 && wid == 0 && l16 == 0) s = row0[c0base + 1024];  // cls row, j=1024
        float p = fast_exp2(s);
        // add p for row l16 into its owning lrow slot: lane with quad == l16>>2, r == l16&3
#pragma unroll
        for (int r = 0; r < 4; ++r)
            if (quad == (l16 >> 2) && (l16 & 3) == r) lrow[r] += p;
        // O rank-1 update: p_r for row gibase+r lives in lane (quad*4 + r)
        const _Float16* v1 = qg + 2 * DIMC + (size_t)1024 * QKVC;
        float vv[4];
#pragma unroll
        for (int ct = 0; ct < 4; ++ct) vv[ct] = (float)v1[ct * 16 + l16];
#pragma unroll
        for (int r = 0; r < 4; ++r) {
            float pr = __shfl(p, quad * 4 + r);
#pragma unroll
            for (int ct = 0; ct < 4; ++ct) oacc[ct][r] += pr * vv[ct];
        }
    }

    // epilogue: 16-lane reduce of l (exact, no pad correction), store att
#pragma unroll
    for (int r = 0; r < 4; ++r) {
        float l = lrow[r];
#pragma unroll
        for (int off = 1; off < 16; off <<= 1) l += __shfl_xor(l, off);
        int gi = q0row + wid * 16 + quad * 4 + r;
        if (gi >= Nn) continue;
        float inv_l = 1.0f / l;
#pragma unroll
        for (int ct = 0; ct < 4; ++ct) {
            att[((size_t)b * Nn + gi) * DIMC + h * HD + ct * 16 + l16] =
                (_Float16)(oacc[ct][r] * inv_l);
        }
    }
}

extern "C" void kernel_launch(void* const* d_in, const int* in_sizes, int n_in,
                              void* d_out, int out_size, void* d_ws, size_t ws_size,
                              hipStream_t stream) {
    const float* x      = (const float*)d_in[1];
    const int*   xpos   = (const int*)d_in[2];
    const float* w_qkv  = (const float*)d_in[4];
    const float* w_proj = (const float*)d_in[5];
    const float* b_proj = (const float*)d_in[6];
    float* out = (float*)d_out;

    char* ws = (char*)d_ws;
    size_t off = 0;
    auto alloc = [&](size_t bytes) {
        char* p = ws + off;
        off += (bytes + 255) & ~(size_t)255;
        return p;
    };
    _Float16* xh     = (_Float16*)alloc((size_t)MPADA * DIMC * 2);   // padded rows for unguarded staging
    _Float16* qkvh   = (_Float16*)alloc((size_t)MROWS * QKVC * 2);
    _Float16* vt     = (_Float16*)alloc((size_t)Bb * Hh * HD * VNP * 2);
    _Float16* wqkvh  = (_Float16*)alloc((size_t)3 * DIMC * DIMC * 2);
    _Float16* wprojh = (_Float16*)alloc((size_t)DIMC * DIMC * 2);
    float* col0      = (float*)alloc((size_t)Bb * Hh * Nn * 4);
    float* row0      = (float*)alloc((size_t)Bb * Hh * Nn * 4);
    float2* trigtab  = (float2*)alloc((size_t)512 * sizeof(float2));
    _Float16* atth   = xh;  // alias: x consumed by QKV GEMM before flash writes att

    {
        int n0 = (MROWS * DIMC) / 4;
        int n1 = (3 * DIMC * DIMC) / 4;
        int n2 = (DIMC * DIMC) / 4;
        int nt = n0 + n1 + n2 + 512;   // +512 table-builder threads
        cvt3_kernel<<<(nt + 255) / 256, 256, 0, stream>>>(
            x, xh, n0, w_qkv, wqkvh, n1, w_proj, wprojh, n2, trigtab);
    }

    // QKV projection -> packed [b,n,3,h,d] (natural GEMM C layout)
    gemm_kernel<0><<<dim3(MPADA / 128, QKVC / 128), 256, 0, stream>>>(
        xh, wqkvh, MROWS, QKVC, DIMC, qkvh, nullptr, nullptr);

    // fused rope (q/k) + V transpose (tokens 0..1023)
    ropevtrans_kernel<<<RBLK + VTBLK, 256, 0, stream>>>(
        qkvh, xpos, col0, row0, vt, trigtab);

    flash_kernel<<<dim3((Nn + 63) / 64, Bb * Hh), 256, 0, stream>>>(
        qkvh, vt, col0, row0, atth);

    gemm_kernel<1><<<dim3(MPADA / 128, DIMC / 128), 256, 0, stream>>>(
        atth, wprojh, MROWS, DIMC, DIMC, nullptr, b_proj, out);
}

// Round 12
// 280.120 us; speedup vs baseline: 1.1409x; 1.0172x over previous
//
#include <hip/hip_runtime.h>

#define Bb 8
#define Nn 1025
#define Hh 12
#define HD 64
#define DIMC 768
#define QKVC 2304          // 3*DIMC, token stride of packed qkv
#define MROWS (Bb * Nn)    // 8200
#define MPADA 8320         // 65*128, padded A rows for unguarded global_load_lds staging
#define VNP 1024           // transposed-V token dim: exactly 8 chunks of 128
#define K1 0.180336880111f // 0.125 * log2(e) — folded into q by rope kernel
#define RBLK ((Bb * Hh * Nn + 3) / 4)   // rope BLOCKS: 98400 waves / 4 per block = 24600
#define VTBLK ((VNP / 64) * Bb * Hh)    // vtrans blocks: 16 * 96 = 1536

typedef _Float16 f16x8 __attribute__((ext_vector_type(8)));
typedef _Float16 f16x4 __attribute__((ext_vector_type(4)));
typedef float f32x4 __attribute__((ext_vector_type(4)));

typedef const __attribute__((address_space(1))) void gv_t;
typedef __attribute__((address_space(3))) void lv_t;

// raw v_exp_f32: skips OCML's denorm-range guard (scores are |s| << 126)
static __device__ __forceinline__ float fast_exp2(float x) {
    return __builtin_amdgcn_exp2f(x);
}

// pack two f32 -> one dword of 2 f16 (single v_cvt_pkrtz_f16_f32)
static __device__ __forceinline__ unsigned int pack2(float a, float b) {
    typedef __fp16 fp16v2 __attribute__((ext_vector_type(2)));
    union { fp16v2 h; unsigned int u; } c;
    c.h = __builtin_amdgcn_cvt_pkrtz(a, b);
    return c.u;
}

// legacy no-underscore spelling (BuiltinsAMDGPU.def, CDNA1-lineage): half4 x half4 -> float4
#define MFMA16(a, b, c) __builtin_amdgcn_mfma_f32_16x16x16f16((a), (b), (c), 0, 0, 0)

// ---------------- fused fp32 -> fp16 convert for 3 tensors + rope trig table ----------------
__global__ void cvt3_kernel(const float* __restrict__ s0, _Float16* __restrict__ d0, int n0,
                            const float* __restrict__ s1, _Float16* __restrict__ d1, int n1,
                            const float* __restrict__ s2, _Float16* __restrict__ d2, int n2,
                            float2* __restrict__ tab) {
    int i = blockIdx.x * 256 + threadIdx.x;
    int nt = n0 + n1 + n2;
    if (i >= nt) {
        int t = i - nt;
        if (t < 512) {
            int p = t >> 4, j = t & 15;
            float ang = (float)p * __expf(-0.28782313662f * (float)j);   // 100^(-j/16)
            tab[t] = make_float2(__cosf(ang), __sinf(ang));
        }
        return;
    }
    const float* s; _Float16* d; int j;
    if (i < n0)           { s = s0; d = d0; j = i; }
    else if (i < n0 + n1) { s = s1; d = d1; j = i - n0; }
    else                  { s = s2; d = d2; j = i - n0 - n1; }
    float4 v = ((const float4*)s)[j];
    f16x4 h;
    h.x = (_Float16)v.x; h.y = (_Float16)v.y; h.z = (_Float16)v.z; h.w = (_Float16)v.w;
    ((f16x4*)d)[j] = h;
}

// ---------------- MFMA GEMM, global_load_lds staging, 2xBK=32 per barrier ----------------
template <int MODE>
__global__ void __launch_bounds__(256) gemm_kernel(
    const _Float16* __restrict__ A, const _Float16* __restrict__ W,
    int M, int Ncols, int K,
    _Float16* __restrict__ outh, const float* __restrict__ bias, float* __restrict__ outf)
{
    __shared__ _Float16 As[2][128 * 32];
    __shared__ _Float16 Ws[2][128 * 32];
    const int tid = threadIdx.x;
    const int wid = tid >> 6, lane = tid & 63;
    const int quad = lane >> 4, l16 = lane & 15;
    const int bm = blockIdx.x * 128, bn = blockIdx.y * 128;
    const int wm = (wid >> 1) * 64, wn = (wid & 1) * 64;

    f32x4 acc[4][4] = {};

    for (int kk = 0; kk < K; kk += 64) {
#pragma unroll
        for (int half = 0; half < 2; ++half) {
#pragma unroll
            for (int c = 0; c < 2; ++c) {
                int s = c * 256 + tid;
                int row = s >> 2, gr = s & 3;
                const _Float16* ga = A + (size_t)(bm + row) * K + kk + half * 32 + gr * 8;
                const _Float16* gw = W + (size_t)(bn + row) * K + kk + half * 32 + gr * 8;
                _Float16* la = As[half] + (size_t)(c * 256 + wid * 64) * 8;
                _Float16* lw = Ws[half] + (size_t)(c * 256 + wid * 64) * 8;
                __builtin_amdgcn_global_load_lds((gv_t*)ga, (lv_t*)la, 16, 0, 0);
                __builtin_amdgcn_global_load_lds((gv_t*)gw, (lv_t*)lw, 16, 0, 0);
            }
        }
        __syncthreads();

#pragma unroll
        for (int half = 0; half < 2; ++half) {
            f16x8 af[4], bf[4];
#pragma unroll
            for (int t = 0; t < 4; ++t) {
                af[t] = *(const f16x8*)(As[half] + (size_t)(wm + t * 16 + l16) * 32 + quad * 8);
                bf[t] = *(const f16x8*)(Ws[half] + (size_t)(wn + t * 16 + l16) * 32 + quad * 8);
            }
#pragma unroll
            for (int tm = 0; tm < 4; ++tm)
#pragma unroll
                for (int tn = 0; tn < 4; ++tn)
                    acc[tm][tn] = __builtin_amdgcn_mfma_f32_16x16x32_f16(af[tm], bf[tn], acc[tm][tn], 0, 0, 0);
        }
        __syncthreads();
    }

#pragma unroll
    for (int tm = 0; tm < 4; ++tm) {
#pragma unroll
        for (int r = 0; r < 4; ++r) {
            int row = bm + wm + tm * 16 + quad * 4 + r;
            if (row >= M) continue;
#pragma unroll
            for (int tn = 0; tn < 4; ++tn) {
                int col = bn + wn + tn * 16 + l16;
                float val = acc[tm][tn][r];
                if (MODE == 0) {
                    outh[(size_t)row * Ncols + col] = (_Float16)val;
                } else {
                    outf[(size_t)row * Ncols + col] = val + bias[col];
                }
            }
        }
    }
}

// ---------------- fused RoPE-2D (+scale-fold, cls dots) and V-transpose ----------------
__global__ void __launch_bounds__(256) ropevtrans_kernel(
    _Float16* __restrict__ qkv, const int* __restrict__ xpos,
    float* __restrict__ col0, float* __restrict__ row0, _Float16* __restrict__ vt,
    const float2* __restrict__ tab)
{
    __shared__ _Float16 Ts[64][72];
    const int blk = blockIdx.x;
    const int tid = threadIdx.x;

    if (blk < RBLK) {
        // ---- rope part: one wave per (b,h,n) ----
        int gw = blk * 4 + (tid >> 6);
        int lane = tid & 63;
        if (gw >= Bb * Hh * Nn) return;
        int n = gw % Nn;
        int bh = gw / Nn;
        int b = bh / Hh, h = bh - b * Hh;

        _Float16* qp = qkv + ((size_t)b * Nn + n) * QKVC + h * HD;
        _Float16* kp = qp + DIMC;
        const _Float16* qp0 = qkv + (size_t)b * Nn * QKVC + h * HD;
        const _Float16* kp0 = qp0 + DIMC;

        float q = (float)qp[lane];
        float k = (float)kp[lane];
        float q0 = (float)qp0[lane];
        float k0 = (float)kp0[lane];

        float dcol = q * k0, drow = q0 * k;
#pragma unroll
        for (int off = 1; off < 64; off <<= 1) {
            dcol += __shfl_xor(dcol, off);
            drow += __shfl_xor(drow, off);
        }
        if (lane == 0) {
            col0[gw] = dcol * K1;   // pre-scaled: flash does p = exp2(value)
            row0[gw] = drow * K1;
        }

        if (n >= 1) {
            int py = xpos[((size_t)b * Nn + n) * 2 + 0];
            int px = xpos[((size_t)b * Nn + n) * 2 + 1];
            int pos = (lane < 32) ? py : px;
            int j = lane & 15;
            float2 cs = tab[((pos & 31) << 4) | j];   // (cos, sin) of pos*100^(-j/16)
            float cv = cs.x, sv = cs.y;
            float qp_ = __shfl_xor(q, 16);
            float kp_ = __shfl_xor(k, 16);
            float sgn = (lane & 16) ? 1.0f : -1.0f;
            qp[lane] = (_Float16)((q * cv + sgn * qp_ * sv) * K1);   // scale folded into q
            kp[lane] = (_Float16)(k * cv + sgn * kp_ * sv);          // k unscaled
        }
    } else {
        // ---- vtrans part: qkv v-slice (tokens 0..1023) -> vt[bh][64][VNP] ----
        int idx = blk - RBLK;
        int nt = idx % (VNP / 64);
        int bh = idx / (VNP / 64);
        int b = bh / Hh, h = bh - b * Hh;
        int n0 = nt * 64;
        const _Float16* vsrc = qkv + (size_t)b * Nn * QKVC + 2 * DIMC + h * HD;
#pragma unroll
        for (int i = 0; i < 2; ++i) {
            int t = tid + i * 256;
            int r = t >> 3, cg = t & 7;
            f16x8 v8 = *(const f16x8*)(vsrc + (size_t)(n0 + r) * QKVC + cg * 8);
            *(f16x8*)&Ts[r][cg * 8] = v8;
        }
        __syncthreads();
#pragma unroll
        for (int i = 0; i < 2; ++i) {
            int t = tid + i * 256;
            int d = t >> 3, ng = t & 7;
            f16x8 o;
#pragma unroll
            for (int s = 0; s < 8; ++s) o[s] = Ts[ng * 8 + s][d];
            *(f16x8*)(vt + ((size_t)bh * HD + d) * VNP + n0 + ng * 8) = o;
        }
    }
}

// ---------------- flash attention R21: Ps deleted via swapped-QK -> mfma16 PV ----------------
// Model (R16/R18 evidence): DS pipe saturated at ~830 cyc/wave-chunk; the Ps
// transpose (32 conflicting b16 writes + 4 b128 reads ~350 cyc) only re-layouts P
// between QK-out and PV-A. Key identity: the A-operand layout of
// mfma_f32_16x16x16f16 (lane: A[row=l16][k=quad*4+{0..3}]) IS the C/D layout of
// the swapped QK mfma(bk,aq) output (lane: S[q=wid*16+l16][k=ct*16+quad*4+r] —
// HW-verified in R13, which PASSED). So: exp2 -> cvt_pkrtz pairs -> feed the f16x4
// directly as PV's A-frag; one 16x16x16 MFMA per (ct,cd); V B-frag is a b64 read
// Vt[cd*16+l16][ct*16+quad*4] (contiguous, 8B-aligned, ~2 lanes/bank). DS/wave-chunk
// ~830 -> ~530; Ps gone (LDS 53.2 -> 35.4 KB). Epilogue = R13's verified
// quad-replicated lsum form.
__global__ void __launch_bounds__(256) flash_kernel(
    const _Float16* __restrict__ qkv, const _Float16* __restrict__ vt,
    const float* __restrict__ col0, const float* __restrict__ row0,
    _Float16* __restrict__ att)
{
    __shared__ _Float16 Ks[128][72];
    __shared__ _Float16 Vt[64][136];

    const int qt = blockIdx.x, bh = blockIdx.y;
    const int b = bh / Hh, h = bh - b * Hh;
    const int tid = threadIdx.x, wid = tid >> 6, lane = tid & 63;
    const int quad = lane >> 4, l16 = lane & 15;
    const int q0row = qt * 64;
    const int c0base = bh * Nn;
    const _Float16* qg = qkv + (size_t)b * Nn * QKVC + h * HD;   // + n*QKVC + d
    const _Float16* kg = qg + DIMC;
    const _Float16* vtg = vt + (size_t)bh * HD * VNP;

    // staging coordinates (fixed per thread)
    const int kR = tid >> 3, kC = (tid & 7) * 8;    // K: rows kR + i*32
    const int vD = tid >> 4, vC = (tid & 15) * 8;   // V: rows vD + i*16

    // stage Q tile into Ks rows 0..63, hoist fragments, release the buffer
#pragma unroll
    for (int i = 0; i < 2; ++i) {
        int t = tid + i * 256;
        int r = t >> 3, cg = t & 7;
        int gr = q0row + r;
        f16x8 v8 = {};
        if (gr < Nn) v8 = *(const f16x8*)(qg + (size_t)gr * QKVC + cg * 8);
        *(f16x8*)&Ks[r][cg * 8] = v8;
    }
    __syncthreads();
    f16x8 aq[2];
#pragma unroll
    for (int ks = 0; ks < 2; ++ks)
        aq[ks] = *(const f16x8*)&Ks[wid * 16 + l16][ks * 32 + quad * 8];
    __syncthreads();

    f32x4 oacc[4] = {};
    float lsum = 0.f;   // partial row-sum for Q-row wid*16 + l16 (this quad's k-slots)

    // prefetch chunk 0 into registers (rows 0..127 all valid -> no guards)
    f16x8 kreg[4], vreg[4];
#pragma unroll
    for (int i = 0; i < 4; ++i) {
        kreg[i] = *(const f16x8*)(kg + (size_t)(kR + i * 32) * QKVC + kC);
        vreg[i] = *(const f16x8*)(vtg + (size_t)(vD + i * 16) * VNP + vC);
    }

    for (int c0 = 0; c0 < VNP; c0 += 128) {
        // commit prefetched registers to LDS
#pragma unroll
        for (int i = 0; i < 4; ++i) {
            *(f16x8*)&Ks[kR + i * 32][kC] = kreg[i];
            *(f16x8*)&Vt[vD + i * 16][vC] = vreg[i];
        }
        __syncthreads();

        // prefetch next chunk (rows <= 1023, unguarded; overlapped with compute)
        int cn = c0 + 128;
        if (cn < VNP) {
#pragma unroll
            for (int i = 0; i < 4; ++i) {
                kreg[i] = *(const f16x8*)(kg + (size_t)(cn + kR + i * 32) * QKVC + kC);
                vreg[i] = *(const f16x8*)(vtg + (size_t)(vD + i * 16) * VNP + cn + vC);
            }
        }

        // S'^T tile (swapped operands): lane (quad,l16) gets
        // S[q = q0row + wid*16 + l16][k = c0 + ct*16 + quad*4 + r]
        f32x4 sacc[8] = {};
#pragma unroll
        for (int ks = 0; ks < 2; ++ks)
#pragma unroll
            for (int ct = 0; ct < 8; ++ct) {
                f16x8 bk = *(const f16x8*)&Ks[ct * 16 + l16][ks * 32 + quad * 8];
                sacc[ct] = __builtin_amdgcn_mfma_f32_16x16x32_f16(bk, aq[ks], sacc[ct], 0, 0, 0);
            }

        // cls column (k==0): only chunk 0; owner quad 0, reg sacc[0][0]
        if (c0 == 0 && quad == 0) {
            int gi = q0row + wid * 16 + l16;
            sacc[0][0] = col0[c0base + (gi < Nn ? gi : 0)];
        }
        // cls row (q==0): only first q-tile, wave 0, lanes l16==0 (all quads)
        if (q0row == 0 && wid == 0 && l16 == 0) {
#pragma unroll
            for (int ct = 0; ct < 8; ++ct)
#pragma unroll
                for (int r = 0; r < 4; ++r)
                    sacc[ct][r] = row0[c0base + c0 + ct * 16 + quad * 4 + r];
        }

        // softmax in-register + PV per 16-k block: pa (f16x4) IS the mfma16 A-frag
#pragma unroll
        for (int ct = 0; ct < 8; ++ct) {
            float p0 = fast_exp2(sacc[ct][0]);
            float p1 = fast_exp2(sacc[ct][1]);
            float p2 = fast_exp2(sacc[ct][2]);
            float p3 = fast_exp2(sacc[ct][3]);
            lsum += (p0 + p1) + (p2 + p3);
            union { f16x4 v; unsigned int u[2]; } pa;
            pa.u[0] = pack2(p0, p1);   // k = ct*16 + quad*4 + {0,1}
            pa.u[1] = pack2(p2, p3);   // k = ct*16 + quad*4 + {2,3}
#pragma unroll
            for (int cd = 0; cd < 4; ++cd) {
                f16x4 bv = *(const f16x4*)&Vt[cd * 16 + l16][ct * 16 + quad * 4];
                oacc[cd] = MFMA16(pa.v, bv, oacc[cd]);
            }
        }
        __syncthreads();   // Ks/Vt consumed before next chunk's commit
    }

    // full row-sum for Q-row wid*16+l16: reduce partials across quads (replicated)
    lsum += __shfl_xor(lsum, 16);
    lsum += __shfl_xor(lsum, 32);

    // ---- token 1024: rank-1 contribution outside the chunk loop ----
    {
        const _Float16* k1 = kg + (size_t)1024 * QKVC;
        f16x8 kk0 = *(const f16x8*)(k1 + quad * 8);
        f16x8 kk1 = *(const f16x8*)(k1 + 32 + quad * 8);
        float part = 0.f;
#pragma unroll
        for (int j = 0; j < 8; ++j)
            part += (float)aq[0][j] * (float)kk0[j] + (float)aq[1][j] * (float)kk1[j];
        part += __shfl_xor(part, 16);
        part += __shfl_xor(part, 32);   // s' for Q row wid*16 + l16 (replicated over quads)
        float s = part;
        if (q0row == 0 && wid == 0 && l16 == 0) s = row0[c0base + 1024];  // cls row, j=1024
        float p = fast_exp2(s);
        lsum += p;   // this lane's own row's contribution (replicated over quads)
        // O rank-1 update: p_r for row gibase+r lives in lane (quad*4 + r)
        const _Float16* v1 = qg + 2 * DIMC + (size_t)1024 * QKVC;
        float vv[4];
#pragma unroll
        for (int cd = 0; cd < 4; ++cd) vv[cd] = (float)v1[cd * 16 + l16];
#pragma unroll
        for (int r = 0; r < 4; ++r) {
            float pr = __shfl(p, quad * 4 + r);
#pragma unroll
            for (int cd = 0; cd < 4; ++cd) oacc[cd][r] += pr * vv[cd];
        }
    }

    // epilogue: l for row quad*4+r lives (replicated) at lane quad*4+r
#pragma unroll
    for (int r = 0; r < 4; ++r) {
        int gi = q0row + wid * 16 + quad * 4 + r;
        if (gi >= Nn) continue;
        float inv_l = 1.0f / __shfl(lsum, quad * 4 + r);
#pragma unroll
        for (int cd = 0; cd < 4; ++cd) {
            att[((size_t)b * Nn + gi) * DIMC + h * HD + cd * 16 + l16] =
                (_Float16)(oacc[cd][r] * inv_l);
        }
    }
}

extern "C" void kernel_launch(void* const* d_in, const int* in_sizes, int n_in,
                              void* d_out, int out_size, void* d_ws, size_t ws_size,
                              hipStream_t stream) {
    const float* x      = (const float*)d_in[1];
    const int*   xpos   = (const int*)d_in[2];
    const float* w_qkv  = (const float*)d_in[4];
    const float* w_proj = (const float*)d_in[5];
    const float* b_proj = (const float*)d_in[6];
    float* out = (float*)d_out;

    char* ws = (char*)d_ws;
    size_t off = 0;
    auto alloc = [&](size_t bytes) {
        char* p = ws + off;
        off += (bytes + 255) & ~(size_t)255;
        return p;
    };
    _Float16* xh     = (_Float16*)alloc((size_t)MPADA * DIMC * 2);   // padded rows for unguarded staging
    _Float16* qkvh   = (_Float16*)alloc((size_t)MROWS * QKVC * 2);
    _Float16* vt     = (_Float16*)alloc((size_t)Bb * Hh * HD * VNP * 2);
    _Float16* wqkvh  = (_Float16*)alloc((size_t)3 * DIMC * DIMC * 2);
    _Float16* wprojh = (_Float16*)alloc((size_t)DIMC * DIMC * 2);
    float* col0      = (float*)alloc((size_t)Bb * Hh * Nn * 4);
    float* row0      = (float*)alloc((size_t)Bb * Hh * Nn * 4);
    float2* trigtab  = (float2*)alloc((size_t)512 * sizeof(float2));
    _Float16* atth   = xh;  // alias: x consumed by QKV GEMM before flash writes att

    {
        int n0 = (MROWS * DIMC) / 4;
        int n1 = (3 * DIMC * DIMC) / 4;
        int n2 = (DIMC * DIMC) / 4;
        int nt = n0 + n1 + n2 + 512;   // +512 table-builder threads
        cvt3_kernel<<<(nt + 255) / 256, 256, 0, stream>>>(
            x, xh, n0, w_qkv, wqkvh, n1, w_proj, wprojh, n2, trigtab);
    }

    // QKV projection -> packed [b,n,3,h,d] (natural GEMM C layout)
    gemm_kernel<0><<<dim3(MPADA / 128, QKVC / 128), 256, 0, stream>>>(
        xh, wqkvh, MROWS, QKVC, DIMC, qkvh, nullptr, nullptr);

    // fused rope (q/k) + V transpose (tokens 0..1023)
    ropevtrans_kernel<<<RBLK + VTBLK, 256, 0, stream>>>(
        qkvh, xpos, col0, row0, vt, trigtab);

    flash_kernel<<<dim3((Nn + 63) / 64, Bb * Hh), 256, 0, stream>>>(
        qkvh, vt, col0, row0, atth);

    gemm_kernel<1><<<dim3(MPADA / 128, DIMC / 128), 256, 0, stream>>>(
        atth, wprojh, MROWS, DIMC, DIMC, nullptr, b_proj, out);
}

// Round 13
// 273.123 us; speedup vs baseline: 1.1702x; 1.0256x over previous
//
#include <hip/hip_runtime.h>

#define Bb 8
#define Nn 1025
#define Hh 12
#define HD 64
#define DIMC 768
#define QKVC 2304          // 3*DIMC, token stride of packed qkv
#define MROWS (Bb * Nn)    // 8200
#define MPADA 8320         // 65*128, padded A rows for unguarded global_load_lds staging
#define VNP 1024           // transposed-V token dim: exactly 8 chunks of 128
#define K1 0.180336880111f // 0.125 * log2(e) — folded into q by rope kernel
#define RBLK ((Bb * Hh * Nn + 3) / 4)   // rope BLOCKS: 98400 waves / 4 per block = 24600
#define VTBLK ((VNP / 64) * Bb * Hh)    // vtrans blocks: 16 * 96 = 1536
#define QTILES 17                       // (Nn+63)/64
#define BHTOT (Bb * Hh)                 // 96

typedef _Float16 f16x8 __attribute__((ext_vector_type(8)));
typedef _Float16 f16x4 __attribute__((ext_vector_type(4)));
typedef float f32x4 __attribute__((ext_vector_type(4)));

typedef const __attribute__((address_space(1))) void gv_t;
typedef __attribute__((address_space(3))) void lv_t;

// raw v_exp_f32: skips OCML's denorm-range guard (scores are |s| << 126)
static __device__ __forceinline__ float fast_exp2(float x) {
    return __builtin_amdgcn_exp2f(x);
}

// pack two f32 -> one dword of 2 f16 (single v_cvt_pkrtz_f16_f32)
static __device__ __forceinline__ unsigned int pack2(float a, float b) {
    typedef __fp16 fp16v2 __attribute__((ext_vector_type(2)));
    union { fp16v2 h; unsigned int u; } c;
    c.h = __builtin_amdgcn_cvt_pkrtz(a, b);
    return c.u;
}

// legacy no-underscore spelling (BuiltinsAMDGPU.def, CDNA1-lineage): half4 x half4 -> float4
#define MFMA16(a, b, c) __builtin_amdgcn_mfma_f32_16x16x16f16((a), (b), (c), 0, 0, 0)

// ---------------- fused fp32 -> fp16 convert for 3 tensors + rope trig table ----------------
__global__ void cvt3_kernel(const float* __restrict__ s0, _Float16* __restrict__ d0, int n0,
                            const float* __restrict__ s1, _Float16* __restrict__ d1, int n1,
                            const float* __restrict__ s2, _Float16* __restrict__ d2, int n2,
                            float2* __restrict__ tab) {
    int i = blockIdx.x * 256 + threadIdx.x;
    int nt = n0 + n1 + n2;
    if (i >= nt) {
        int t = i - nt;
        if (t < 512) {
            int p = t >> 4, j = t & 15;
            float ang = (float)p * __expf(-0.28782313662f * (float)j);   // 100^(-j/16)
            tab[t] = make_float2(__cosf(ang), __sinf(ang));
        }
        return;
    }
    const float* s; _Float16* d; int j;
    if (i < n0)           { s = s0; d = d0; j = i; }
    else if (i < n0 + n1) { s = s1; d = d1; j = i - n0; }
    else                  { s = s2; d = d2; j = i - n0 - n1; }
    float4 v = ((const float4*)s)[j];
    f16x4 h;
    h.x = (_Float16)v.x; h.y = (_Float16)v.y; h.z = (_Float16)v.z; h.w = (_Float16)v.w;
    ((f16x4*)d)[j] = h;
}

// ---------------- MFMA GEMM, global_load_lds staging, 2xBK=32 per barrier ----------------
template <int MODE>
__global__ void __launch_bounds__(256) gemm_kernel(
    const _Float16* __restrict__ A, const _Float16* __restrict__ W,
    int M, int Ncols, int K,
    _Float16* __restrict__ outh, const float* __restrict__ bias, float* __restrict__ outf)
{
    __shared__ _Float16 As[2][128 * 32];
    __shared__ _Float16 Ws[2][128 * 32];
    const int tid = threadIdx.x;
    const int wid = tid >> 6, lane = tid & 63;
    const int quad = lane >> 4, l16 = lane & 15;
    const int bm = blockIdx.x * 128, bn = blockIdx.y * 128;
    const int wm = (wid >> 1) * 64, wn = (wid & 1) * 64;

    f32x4 acc[4][4] = {};

    for (int kk = 0; kk < K; kk += 64) {
#pragma unroll
        for (int half = 0; half < 2; ++half) {
#pragma unroll
            for (int c = 0; c < 2; ++c) {
                int s = c * 256 + tid;
                int row = s >> 2, gr = s & 3;
                const _Float16* ga = A + (size_t)(bm + row) * K + kk + half * 32 + gr * 8;
                const _Float16* gw = W + (size_t)(bn + row) * K + kk + half * 32 + gr * 8;
                _Float16* la = As[half] + (size_t)(c * 256 + wid * 64) * 8;
                _Float16* lw = Ws[half] + (size_t)(c * 256 + wid * 64) * 8;
                __builtin_amdgcn_global_load_lds((gv_t*)ga, (lv_t*)la, 16, 0, 0);
                __builtin_amdgcn_global_load_lds((gv_t*)gw, (lv_t*)lw, 16, 0, 0);
            }
        }
        __syncthreads();

#pragma unroll
        for (int half = 0; half < 2; ++half) {
            f16x8 af[4], bf[4];
#pragma unroll
            for (int t = 0; t < 4; ++t) {
                af[t] = *(const f16x8*)(As[half] + (size_t)(wm + t * 16 + l16) * 32 + quad * 8);
                bf[t] = *(const f16x8*)(Ws[half] + (size_t)(wn + t * 16 + l16) * 32 + quad * 8);
            }
#pragma unroll
            for (int tm = 0; tm < 4; ++tm)
#pragma unroll
                for (int tn = 0; tn < 4; ++tn)
                    acc[tm][tn] = __builtin_amdgcn_mfma_f32_16x16x32_f16(af[tm], bf[tn], acc[tm][tn], 0, 0, 0);
        }
        __syncthreads();
    }

#pragma unroll
    for (int tm = 0; tm < 4; ++tm) {
#pragma unroll
        for (int r = 0; r < 4; ++r) {
            int row = bm + wm + tm * 16 + quad * 4 + r;
            if (row >= M) continue;
#pragma unroll
            for (int tn = 0; tn < 4; ++tn) {
                int col = bn + wn + tn * 16 + l16;
                float val = acc[tm][tn][r];
                if (MODE == 0) {
                    outh[(size_t)row * Ncols + col] = (_Float16)val;
                } else {
                    outf[(size_t)row * Ncols + col] = val + bias[col];
                }
            }
        }
    }
}

// ---------------- fused RoPE-2D (+scale-fold, cls dots) and V-transpose ----------------
__global__ void __launch_bounds__(256) ropevtrans_kernel(
    _Float16* __restrict__ qkv, const int* __restrict__ xpos,
    float* __restrict__ col0, float* __restrict__ row0, _Float16* __restrict__ vt,
    const float2* __restrict__ tab)
{
    __shared__ _Float16 Ts[64][72];
    const int blk = blockIdx.x;
    const int tid = threadIdx.x;

    if (blk < RBLK) {
        // ---- rope part: one wave per (b,h,n) ----
        int gw = blk * 4 + (tid >> 6);
        int lane = tid & 63;
        if (gw >= Bb * Hh * Nn) return;
        int n = gw % Nn;
        int bh = gw / Nn;
        int b = bh / Hh, h = bh - b * Hh;

        _Float16* qp = qkv + ((size_t)b * Nn + n) * QKVC + h * HD;
        _Float16* kp = qp + DIMC;
        const _Float16* qp0 = qkv + (size_t)b * Nn * QKVC + h * HD;
        const _Float16* kp0 = qp0 + DIMC;

        float q = (float)qp[lane];
        float k = (float)kp[lane];
        float q0 = (float)qp0[lane];
        float k0 = (float)kp0[lane];

        float dcol = q * k0, drow = q0 * k;
#pragma unroll
        for (int off = 1; off < 64; off <<= 1) {
            dcol += __shfl_xor(dcol, off);
            drow += __shfl_xor(drow, off);
        }
        if (lane == 0) {
            col0[gw] = dcol * K1;   // pre-scaled: flash does p = exp2(value)
            row0[gw] = drow * K1;
        }

        if (n >= 1) {
            int py = xpos[((size_t)b * Nn + n) * 2 + 0];
            int px = xpos[((size_t)b * Nn + n) * 2 + 1];
            int pos = (lane < 32) ? py : px;
            int j = lane & 15;
            float2 cs = tab[((pos & 31) << 4) | j];   // (cos, sin) of pos*100^(-j/16)
            float cv = cs.x, sv = cs.y;
            float qp_ = __shfl_xor(q, 16);
            float kp_ = __shfl_xor(k, 16);
            float sgn = (lane & 16) ? 1.0f : -1.0f;
            qp[lane] = (_Float16)((q * cv + sgn * qp_ * sv) * K1);   // scale folded into q
            kp[lane] = (_Float16)(k * cv + sgn * kp_ * sv);          // k unscaled
        }
    } else {
        // ---- vtrans part: qkv v-slice (tokens 0..1023) -> vt[bh][64][VNP] ----
        int idx = blk - RBLK;
        int nt = idx % (VNP / 64);
        int bh = idx / (VNP / 64);
        int b = bh / Hh, h = bh - b * Hh;
        int n0 = nt * 64;
        const _Float16* vsrc = qkv + (size_t)b * Nn * QKVC + 2 * DIMC + h * HD;
#pragma unroll
        for (int i = 0; i < 2; ++i) {
            int t = tid + i * 256;
            int r = t >> 3, cg = t & 7;
            f16x8 v8 = *(const f16x8*)(vsrc + (size_t)(n0 + r) * QKVC + cg * 8);
            *(f16x8*)&Ts[r][cg * 8] = v8;
        }
        __syncthreads();
#pragma unroll
        for (int i = 0; i < 2; ++i) {
            int t = tid + i * 256;
            int d = t >> 3, ng = t & 7;
            f16x8 o;
#pragma unroll
            for (int s = 0; s < 8; ++s) o[s] = Ts[ng * 8 + s][d];
            *(f16x8*)(vt + ((size_t)bh * HD + d) * VNP + n0 + ng * 8) = o;
        }
    }
}

// ---------------- flash attention R23: R22 + XCD-aware block swizzle (T1) ----------------
// R22 measured 70.3us, FETCH 105MB vs ~38MB ideal: grid (qt,bh) with qt-fastest
// round-robins the 17 q-tiles sharing one bh's K/vt across the 8 XCDs -> each
// per-XCD L2 fetches its own K/vt copy (13 + ~8x24MB == measured 105MB). R23:
// 1-D grid, bid = bh%8 + 8*(qt + 17*(bh/8)) inverted in-kernel, so all 17 q-tiles
// of a bh have bid == bh (mod 8) -> same XCD -> K/vt fetched once per L2.
// Bijective: 17*96 = 1632 = 8*204. Body identical to R22.
__global__ void __launch_bounds__(256) flash_kernel(
    const _Float16* __restrict__ qkv, const _Float16* __restrict__ vt,
    const float* __restrict__ col0, const float* __restrict__ row0,
    _Float16* __restrict__ att)
{
    __shared__ _Float16 Ks[128][72];
    __shared__ _Float16 Vt[64][136];

    // XCD swizzle decode: all blocks with equal bid%8 share an XCD (round-robin)
    const int bid = blockIdx.x;
    const int xcd = bid & 7;
    const int t8 = bid >> 3;           // 0..203
    const int qt = t8 % QTILES;
    const int bh = xcd + 8 * (t8 / QTILES);

    const int b = bh / Hh, h = bh - b * Hh;
    const int tid = threadIdx.x, wid = tid >> 6, lane = tid & 63;
    const int quad = lane >> 4, l16 = lane & 15;
    const int q0row = qt * 64;
    const int c0base = bh * Nn;
    const _Float16* qg = qkv + (size_t)b * Nn * QKVC + h * HD;   // + n*QKVC + d
    const _Float16* kg = qg + DIMC;
    const _Float16* vtg = vt + (size_t)bh * HD * VNP;

    // staging coordinates (fixed per thread)
    const int kR = tid >> 3, kC = (tid & 7) * 8;    // K: rows kR + i*32
    const int vD = tid >> 4, vC = (tid & 15) * 8;   // V: rows vD + i*16

    // stage Q tile into Ks rows 0..63, hoist fragments, release the buffer
#pragma unroll
    for (int i = 0; i < 2; ++i) {
        int t = tid + i * 256;
        int r = t >> 3, cg = t & 7;
        int gr = q0row + r;
        f16x8 v8 = {};
        if (gr < Nn) v8 = *(const f16x8*)(qg + (size_t)gr * QKVC + cg * 8);
        *(f16x8*)&Ks[r][cg * 8] = v8;
    }
    __syncthreads();
    f16x8 aq[2];
#pragma unroll
    for (int ks = 0; ks < 2; ++ks)
        aq[ks] = *(const f16x8*)&Ks[wid * 16 + l16][ks * 32 + quad * 8];
    __syncthreads();

    f32x4 oacc[4] = {};
    float lsum = 0.f;   // partial row-sum for Q-row wid*16 + l16 (this quad's k-slots)

    // prefetch chunk 0 into registers (rows 0..127 all valid -> no guards)
    f16x8 kreg[4], vreg[4];
#pragma unroll
    for (int i = 0; i < 4; ++i) {
        kreg[i] = *(const f16x8*)(kg + (size_t)(kR + i * 32) * QKVC + kC);
        vreg[i] = *(const f16x8*)(vtg + (size_t)(vD + i * 16) * VNP + vC);
    }

    for (int c0 = 0; c0 < VNP; c0 += 128) {
        // commit prefetched registers to LDS
#pragma unroll
        for (int i = 0; i < 4; ++i) {
            *(f16x8*)&Ks[kR + i * 32][kC] = kreg[i];
            *(f16x8*)&Vt[vD + i * 16][vC] = vreg[i];
        }
        __syncthreads();

        // prefetch next chunk (rows <= 1023, unguarded; overlapped with compute)
        int cn = c0 + 128;
        if (cn < VNP) {
#pragma unroll
            for (int i = 0; i < 4; ++i) {
                kreg[i] = *(const f16x8*)(kg + (size_t)(cn + kR + i * 32) * QKVC + kC);
                vreg[i] = *(const f16x8*)(vtg + (size_t)(vD + i * 16) * VNP + cn + vC);
            }
        }

        // S'^T tile (swapped operands): lane (quad,l16) gets
        // S[q = q0row + wid*16 + l16][k = c0 + ct*16 + quad*4 + r]
        f32x4 sacc[8] = {};
#pragma unroll
        for (int ks = 0; ks < 2; ++ks)
#pragma unroll
            for (int ct = 0; ct < 8; ++ct) {
                f16x8 bk = *(const f16x8*)&Ks[ct * 16 + l16][ks * 32 + quad * 8];
                sacc[ct] = __builtin_amdgcn_mfma_f32_16x16x32_f16(bk, aq[ks], sacc[ct], 0, 0, 0);
            }

        // cls column (k==0): only chunk 0; owner quad 0, reg sacc[0][0]
        if (c0 == 0 && quad == 0) {
            int gi = q0row + wid * 16 + l16;
            sacc[0][0] = col0[c0base + (gi < Nn ? gi : 0)];
        }
        // cls row (q==0): only first q-tile, wave 0, lanes l16==0 (all quads)
        if (q0row == 0 && wid == 0 && l16 == 0) {
#pragma unroll
            for (int ct = 0; ct < 8; ++ct)
#pragma unroll
                for (int r = 0; r < 4; ++r)
                    sacc[ct][r] = row0[c0base + c0 + ct * 16 + quad * 4 + r];
        }

        // softmax in-register + PV per 16-k block: pa (f16x4) IS the mfma16 A-frag
#pragma unroll
        for (int ct = 0; ct < 8; ++ct) {
            float p0 = fast_exp2(sacc[ct][0]);
            float p1 = fast_exp2(sacc[ct][1]);
            float p2 = fast_exp2(sacc[ct][2]);
            float p3 = fast_exp2(sacc[ct][3]);
            lsum += (p0 + p1) + (p2 + p3);
            union { f16x4 v; unsigned int u[2]; } pa;
            pa.u[0] = pack2(p0, p1);   // k = ct*16 + quad*4 + {0,1}
            pa.u[1] = pack2(p2, p3);   // k = ct*16 + quad*4 + {2,3}
#pragma unroll
            for (int cd = 0; cd < 4; ++cd) {
                f16x4 bv = *(const f16x4*)&Vt[cd * 16 + l16][ct * 16 + quad * 4];
                oacc[cd] = MFMA16(pa.v, bv, oacc[cd]);
            }
        }
        __syncthreads();   // Ks/Vt consumed before next chunk's commit
    }

    // full row-sum for Q-row wid*16+l16: reduce partials across quads (replicated)
    lsum += __shfl_xor(lsum, 16);
    lsum += __shfl_xor(lsum, 32);

    // ---- token 1024: rank-1 contribution outside the chunk loop ----
    {
        const _Float16* k1 = kg + (size_t)1024 * QKVC;
        f16x8 kk0 = *(const f16x8*)(k1 + quad * 8);
        f16x8 kk1 = *(const f16x8*)(k1 + 32 + quad * 8);
        float part = 0.f;
#pragma unroll
        for (int j = 0; j < 8; ++j)
            part += (float)aq[0][j] * (float)kk0[j] + (float)aq[1][j] * (float)kk1[j];
        part += __shfl_xor(part, 16);
        part += __shfl_xor(part, 32);   // s' for Q row wid*16 + l16 (replicated over quads)
        float s = part;
        if (q0row == 0 && wid == 0 && l16 == 0) s = row0[c0base + 1024];  // cls row, j=1024
        float p = fast_exp2(s);
        lsum += p;   // this lane's own row's contribution (replicated over quads)
        // O rank-1 update: p_r for row gibase+r lives in lane (quad*4 + r)
        const _Float16* v1 = qg + 2 * DIMC + (size_t)1024 * QKVC;
        float vv[4];
#pragma unroll
        for (int cd = 0; cd < 4; ++cd) vv[cd] = (float)v1[cd * 16 + l16];
#pragma unroll
        for (int r = 0; r < 4; ++r) {
            float pr = __shfl(p, quad * 4 + r);
#pragma unroll
            for (int cd = 0; cd < 4; ++cd) oacc[cd][r] += pr * vv[cd];
        }
    }

    // epilogue: l for row quad*4+r lives (replicated) at lane quad*4+r
#pragma unroll
    for (int r = 0; r < 4; ++r) {
        int gi = q0row + wid * 16 + quad * 4 + r;
        if (gi >= Nn) continue;
        float inv_l = 1.0f / __shfl(lsum, quad * 4 + r);
#pragma unroll
        for (int cd = 0; cd < 4; ++cd) {
            att[((size_t)b * Nn + gi) * DIMC + h * HD + cd * 16 + l16] =
                (_Float16)(oacc[cd][r] * inv_l);
        }
    }
}

extern "C" void kernel_launch(void* const* d_in, const int* in_sizes, int n_in,
                              void* d_out, int out_size, void* d_ws, size_t ws_size,
                              hipStream_t stream) {
    const float* x      = (const float*)d_in[1];
    const int*   xpos   = (const int*)d_in[2];
    const float* w_qkv  = (const float*)d_in[4];
    const float* w_proj = (const float*)d_in[5];
    const float* b_proj = (const float*)d_in[6];
    float* out = (float*)d_out;

    char* ws = (char*)d_ws;
    size_t off = 0;
    auto alloc = [&](size_t bytes) {
        char* p = ws + off;
        off += (bytes + 255) & ~(size_t)255;
        return p;
    };
    _Float16* xh     = (_Float16*)alloc((size_t)MPADA * DIMC * 2);   // padded rows for unguarded staging
    _Float16* qkvh   = (_Float16*)alloc((size_t)MROWS * QKVC * 2);
    _Float16* vt     = (_Float16*)alloc((size_t)Bb * Hh * HD * VNP * 2);
    _Float16* wqkvh  = (_Float16*)alloc((size_t)3 * DIMC * DIMC * 2);
    _Float16* wprojh = (_Float16*)alloc((size_t)DIMC * DIMC * 2);
    float* col0      = (float*)alloc((size_t)Bb * Hh * Nn * 4);
    float* row0      = (float*)alloc((size_t)Bb * Hh * Nn * 4);
    float2* trigtab  = (float2*)alloc((size_t)512 * sizeof(float2));
    _Float16* atth   = xh;  // alias: x consumed by QKV GEMM before flash writes att

    {
        int n0 = (MROWS * DIMC) / 4;
        int n1 = (3 * DIMC * DIMC) / 4;
        int n2 = (DIMC * DIMC) / 4;
        int nt = n0 + n1 + n2 + 512;   // +512 table-builder threads
        cvt3_kernel<<<(nt + 255) / 256, 256, 0, stream>>>(
            x, xh, n0, w_qkv, wqkvh, n1, w_proj, wprojh, n2, trigtab);
    }

    // QKV projection -> packed [b,n,3,h,d] (natural GEMM C layout)
    gemm_kernel<0><<<dim3(MPADA / 128, QKVC / 128), 256, 0, stream>>>(
        xh, wqkvh, MROWS, QKVC, DIMC, qkvh, nullptr, nullptr);

    // fused rope (q/k) + V transpose (tokens 0..1023)
    ropevtrans_kernel<<<RBLK + VTBLK, 256, 0, stream>>>(
        qkvh, xpos, col0, row0, vt, trigtab);

    // XCD-swizzled 1-D grid: 17*96 = 1632 blocks
    flash_kernel<<<QTILES * BHTOT, 256, 0, stream>>>(
        qkvh, vt, col0, row0, atth);

    gemm_kernel<1><<<dim3(MPADA / 128, DIMC / 128), 256, 0, stream>>>(
        atth, wprojh, MROWS, DIMC, DIMC, nullptr, b_proj, out);
}

// Round 14
// 267.712 us; speedup vs baseline: 1.1938x; 1.0202x over previous
//
#include <hip/hip_runtime.h>

#define Bb 8
#define Nn 1025
#define Hh 12
#define HD 64
#define DIMC 768
#define QKVC 2304          // 3*DIMC, token stride of packed qkv
#define MROWS (Bb * Nn)    // 8200
#define MPADA 8320         // 65*128, padded A rows for unguarded global_load_lds staging
#define VNP 1024           // transposed-V token dim: exactly 8 chunks of 128
#define K1 0.180336880111f // 0.125 * log2(e) — folded into q by rope kernel
#define RBLK ((Bb * Hh * Nn + 3) / 4)   // rope BLOCKS: 98400 waves / 4 per block = 24600
#define VTBLK ((VNP / 64) * Bb * Hh)    // vtrans blocks: 16 * 96 = 1536
#define QT128 9                         // ceil(Nn/128)
#define BHTOT (Bb * Hh)                 // 96

typedef _Float16 f16x8 __attribute__((ext_vector_type(8)));
typedef _Float16 f16x4 __attribute__((ext_vector_type(4)));
typedef float f32x4 __attribute__((ext_vector_type(4)));

typedef const __attribute__((address_space(1))) void gv_t;
typedef __attribute__((address_space(3))) void lv_t;

// raw v_exp_f32: skips OCML's denorm-range guard (scores are |s| << 126)
static __device__ __forceinline__ float fast_exp2(float x) {
    return __builtin_amdgcn_exp2f(x);
}

// pack two f32 -> one dword of 2 f16 (single v_cvt_pkrtz_f16_f32)
static __device__ __forceinline__ unsigned int pack2(float a, float b) {
    typedef __fp16 fp16v2 __attribute__((ext_vector_type(2)));
    union { fp16v2 h; unsigned int u; } c;
    c.h = __builtin_amdgcn_cvt_pkrtz(a, b);
    return c.u;
}

// legacy no-underscore spelling (BuiltinsAMDGPU.def, CDNA1-lineage): half4 x half4 -> float4
#define MFMA16(a, b, c) __builtin_amdgcn_mfma_f32_16x16x16f16((a), (b), (c), 0, 0, 0)

// ---------------- fused fp32 -> fp16 convert for 3 tensors + rope trig table ----------------
__global__ void cvt3_kernel(const float* __restrict__ s0, _Float16* __restrict__ d0, int n0,
                            const float* __restrict__ s1, _Float16* __restrict__ d1, int n1,
                            const float* __restrict__ s2, _Float16* __restrict__ d2, int n2,
                            float2* __restrict__ tab) {
    int i = blockIdx.x * 256 + threadIdx.x;
    int nt = n0 + n1 + n2;
    if (i >= nt) {
        int t = i - nt;
        if (t < 512) {
            int p = t >> 4, j = t & 15;
            float ang = (float)p * __expf(-0.28782313662f * (float)j);   // 100^(-j/16)
            tab[t] = make_float2(__cosf(ang), __sinf(ang));
        }
        return;
    }
    const float* s; _Float16* d; int j;
    if (i < n0)           { s = s0; d = d0; j = i; }
    else if (i < n0 + n1) { s = s1; d = d1; j = i - n0; }
    else                  { s = s2; d = d2; j = i - n0 - n1; }
    float4 v = ((const float4*)s)[j];
    f16x4 h;
    h.x = (_Float16)v.x; h.y = (_Float16)v.y; h.z = (_Float16)v.z; h.w = (_Float16)v.w;
    ((f16x4*)d)[j] = h;
}

// ---------------- MFMA GEMM, global_load_lds staging, 2xBK=32 per barrier ----------------
template <int MODE>
__global__ void __launch_bounds__(256) gemm_kernel(
    const _Float16* __restrict__ A, const _Float16* __restrict__ W,
    int M, int Ncols, int K,
    _Float16* __restrict__ outh, const float* __restrict__ bias, float* __restrict__ outf)
{
    __shared__ _Float16 As[2][128 * 32];
    __shared__ _Float16 Ws[2][128 * 32];
    const int tid = threadIdx.x;
    const int wid = tid >> 6, lane = tid & 63;
    const int quad = lane >> 4, l16 = lane & 15;
    const int bm = blockIdx.x * 128, bn = blockIdx.y * 128;
    const int wm = (wid >> 1) * 64, wn = (wid & 1) * 64;

    f32x4 acc[4][4] = {};

    for (int kk = 0; kk < K; kk += 64) {
#pragma unroll
        for (int half = 0; half < 2; ++half) {
#pragma unroll
            for (int c = 0; c < 2; ++c) {
                int s = c * 256 + tid;
                int row = s >> 2, gr = s & 3;
                const _Float16* ga = A + (size_t)(bm + row) * K + kk + half * 32 + gr * 8;
                const _Float16* gw = W + (size_t)(bn + row) * K + kk + half * 32 + gr * 8;
                _Float16* la = As[half] + (size_t)(c * 256 + wid * 64) * 8;
                _Float16* lw = Ws[half] + (size_t)(c * 256 + wid * 64) * 8;
                __builtin_amdgcn_global_load_lds((gv_t*)ga, (lv_t*)la, 16, 0, 0);
                __builtin_amdgcn_global_load_lds((gv_t*)gw, (lv_t*)lw, 16, 0, 0);
            }
        }
        __syncthreads();

#pragma unroll
        for (int half = 0; half < 2; ++half) {
            f16x8 af[4], bf[4];
#pragma unroll
            for (int t = 0; t < 4; ++t) {
                af[t] = *(const f16x8*)(As[half] + (size_t)(wm + t * 16 + l16) * 32 + quad * 8);
                bf[t] = *(const f16x8*)(Ws[half] + (size_t)(wn + t * 16 + l16) * 32 + quad * 8);
            }
#pragma unroll
            for (int tm = 0; tm < 4; ++tm)
#pragma unroll
                for (int tn = 0; tn < 4; ++tn)
                    acc[tm][tn] = __builtin_amdgcn_mfma_f32_16x16x32_f16(af[tm], bf[tn], acc[tm][tn], 0, 0, 0);
        }
        __syncthreads();
    }

#pragma unroll
    for (int tm = 0; tm < 4; ++tm) {
#pragma unroll
        for (int r = 0; r < 4; ++r) {
            int row = bm + wm + tm * 16 + quad * 4 + r;
            if (row >= M) continue;
#pragma unroll
            for (int tn = 0; tn < 4; ++tn) {
                int col = bn + wn + tn * 16 + l16;
                float val = acc[tm][tn][r];
                if (MODE == 0) {
                    outh[(size_t)row * Ncols + col] = (_Float16)val;
                } else {
                    outf[(size_t)row * Ncols + col] = val + bias[col];
                }
            }
        }
    }
}

// ---------------- fused RoPE-2D (+scale-fold, cls dots) and V-transpose ----------------
__global__ void __launch_bounds__(256) ropevtrans_kernel(
    _Float16* __restrict__ qkv, const int* __restrict__ xpos,
    float* __restrict__ col0, float* __restrict__ row0, _Float16* __restrict__ vt,
    const float2* __restrict__ tab)
{
    __shared__ _Float16 Ts[64][72];
    const int blk = blockIdx.x;
    const int tid = threadIdx.x;

    if (blk < RBLK) {
        // ---- rope part: one wave per (b,h,n) ----
        int gw = blk * 4 + (tid >> 6);
        int lane = tid & 63;
        if (gw >= Bb * Hh * Nn) return;
        int n = gw % Nn;
        int bh = gw / Nn;
        int b = bh / Hh, h = bh - b * Hh;

        _Float16* qp = qkv + ((size_t)b * Nn + n) * QKVC + h * HD;
        _Float16* kp = qp + DIMC;
        const _Float16* qp0 = qkv + (size_t)b * Nn * QKVC + h * HD;
        const _Float16* kp0 = qp0 + DIMC;

        float q = (float)qp[lane];
        float k = (float)kp[lane];
        float q0 = (float)qp0[lane];
        float k0 = (float)kp0[lane];

        float dcol = q * k0, drow = q0 * k;
#pragma unroll
        for (int off = 1; off < 64; off <<= 1) {
            dcol += __shfl_xor(dcol, off);
            drow += __shfl_xor(drow, off);
        }
        if (lane == 0) {
            col0[gw] = dcol * K1;   // pre-scaled: flash does p = exp2(value)
            row0[gw] = drow * K1;
        }

        if (n >= 1) {
            int py = xpos[((size_t)b * Nn + n) * 2 + 0];
            int px = xpos[((size_t)b * Nn + n) * 2 + 1];
            int pos = (lane < 32) ? py : px;
            int j = lane & 15;
            float2 cs = tab[((pos & 31) << 4) | j];   // (cos, sin) of pos*100^(-j/16)
            float cv = cs.x, sv = cs.y;
            float qp_ = __shfl_xor(q, 16);
            float kp_ = __shfl_xor(k, 16);
            float sgn = (lane & 16) ? 1.0f : -1.0f;
            qp[lane] = (_Float16)((q * cv + sgn * qp_ * sv) * K1);   // scale folded into q
            kp[lane] = (_Float16)(k * cv + sgn * kp_ * sv);          // k unscaled
        }
    } else {
        // ---- vtrans part: qkv v-slice (tokens 0..1023) -> vt[bh][64][VNP] ----
        int idx = blk - RBLK;
        int nt = idx % (VNP / 64);
        int bh = idx / (VNP / 64);
        int b = bh / Hh, h = bh - b * Hh;
        int n0 = nt * 64;
        const _Float16* vsrc = qkv + (size_t)b * Nn * QKVC + 2 * DIMC + h * HD;
#pragma unroll
        for (int i = 0; i < 2; ++i) {
            int t = tid + i * 256;
            int r = t >> 3, cg = t & 7;
            f16x8 v8 = *(const f16x8*)(vsrc + (size_t)(n0 + r) * QKVC + cg * 8);
            *(f16x8*)&Ts[r][cg * 8] = v8;
        }
        __syncthreads();
#pragma unroll
        for (int i = 0; i < 2; ++i) {
            int t = tid + i * 256;
            int d = t >> 3, ng = t & 7;
            f16x8 o;
#pragma unroll
            for (int s = 0; s < 8; ++s) o[s] = Ts[ng * 8 + s][d];
            *(f16x8*)(vt + ((size_t)bh * HD + d) * VNP + n0 + ng * 8) = o;
        }
    }
}

// ---------------- flash attention R24: QBLK=128 on the R22 (Ps-free) structure ----------------
// R23: FETCH 105->19MB (XCD swizzle verified), flash LDS+VALU bound. R24 halves
// staged-bytes per output: 128 Q-rows/block (aq[2][2]); every bk (b128) and bv (b64)
// read feeds TWO MFMAs (one per q-half). This failed in R15 (register blowup: needed
// pk[2][8][2]) and R18 (Ps[128][72] pushed LDS to 54KB -> 2 blocks/CU). Both causes
// are gone: R22's fused per-ct softmax->PV has no pk array, and Ps is deleted.
// ct processed in two groups of 4 keeps sacc[2][4]=32 regs; LDS stays 35840B
// (4 blocks/CU). Grid 17x96 -> 9x96=864, XCD-swizzled (864=8x108). cls patches and
// token-1024/store epilogue are the R22 forms wrapped in a q2 loop.
__global__ void __launch_bounds__(256) flash_kernel(
    const _Float16* __restrict__ qkv, const _Float16* __restrict__ vt,
    const float* __restrict__ col0, const float* __restrict__ row0,
    _Float16* __restrict__ att)
{
    __shared__ _Float16 Ks[128][72];
    __shared__ _Float16 Vt[64][136];

    // XCD swizzle decode: all q-tiles of one bh share bid%8 -> same XCD
    const int bid = blockIdx.x;
    const int xcd = bid & 7;
    const int t8 = bid >> 3;            // 0..107
    const int qt = t8 % QT128;
    const int bh = xcd + 8 * (t8 / QT128);

    const int b = bh / Hh, h = bh - b * Hh;
    const int tid = threadIdx.x, wid = tid >> 6, lane = tid & 63;
    const int quad = lane >> 4, l16 = lane & 15;
    const int q0row = qt * 128;
    const int c0base = bh * Nn;
    const _Float16* qg = qkv + (size_t)b * Nn * QKVC + h * HD;   // + n*QKVC + d
    const _Float16* kg = qg + DIMC;
    const _Float16* vtg = vt + (size_t)bh * HD * VNP;

    // staging coordinates (fixed per thread)
    const int kR = tid >> 3, kC = (tid & 7) * 8;    // K: rows kR + i*32
    const int vD = tid >> 4, vC = (tid & 15) * 8;   // V: rows vD + i*16

    // stage 128 Q rows into Ks, hoist both halves' fragments, release the buffer
#pragma unroll
    for (int i = 0; i < 4; ++i) {
        int t = tid + i * 256;
        int r = t >> 3, cg = t & 7;
        int gr = q0row + r;
        f16x8 v8 = {};
        if (gr < Nn) v8 = *(const f16x8*)(qg + (size_t)gr * QKVC + cg * 8);
        *(f16x8*)&Ks[r][cg * 8] = v8;
    }
    __syncthreads();
    f16x8 aq[2][2];
#pragma unroll
    for (int q2 = 0; q2 < 2; ++q2)
#pragma unroll
        for (int ks = 0; ks < 2; ++ks)
            aq[q2][ks] = *(const f16x8*)&Ks[q2 * 64 + wid * 16 + l16][ks * 32 + quad * 8];
    __syncthreads();

    f32x4 oacc[2][4] = {};          // [q2][cd]
    float lsum[2] = {0.f, 0.f};     // this quad's k-slot partials, row q2*64+wid*16+l16

    // prefetch chunk 0 into registers (rows 0..127 all valid -> no guards)
    f16x8 kreg[4], vreg[4];
#pragma unroll
    for (int i = 0; i < 4; ++i) {
        kreg[i] = *(const f16x8*)(kg + (size_t)(kR + i * 32) * QKVC + kC);
        vreg[i] = *(const f16x8*)(vtg + (size_t)(vD + i * 16) * VNP + vC);
    }

    for (int c0 = 0; c0 < VNP; c0 += 128) {
        // commit prefetched registers to LDS
#pragma unroll
        for (int i = 0; i < 4; ++i) {
            *(f16x8*)&Ks[kR + i * 32][kC] = kreg[i];
            *(f16x8*)&Vt[vD + i * 16][vC] = vreg[i];
        }
        __syncthreads();

        // prefetch next chunk (rows <= 1023, unguarded; overlapped with compute)
        int cn = c0 + 128;
        if (cn < VNP) {
#pragma unroll
            for (int i = 0; i < 4; ++i) {
                kreg[i] = *(const f16x8*)(kg + (size_t)(cn + kR + i * 32) * QKVC + kC);
                vreg[i] = *(const f16x8*)(vtg + (size_t)(vD + i * 16) * VNP + cn + vC);
            }
        }

        // two ct-groups of 4; sacc[2][4] reused (caps register peak)
#pragma unroll
        for (int sub = 0; sub < 2; ++sub) {
            // S'^T both halves (swapped operands): lane (quad,l16) gets
            // S[q = q0row + q2*64 + wid*16 + l16][k = c0 + ct*16 + quad*4 + r]
            f32x4 sacc[2][4] = {};
#pragma unroll
            for (int ks = 0; ks < 2; ++ks)
#pragma unroll
                for (int ctl = 0; ctl < 4; ++ctl) {
                    int ct = sub * 4 + ctl;
                    f16x8 bk = *(const f16x8*)&Ks[ct * 16 + l16][ks * 32 + quad * 8];
                    sacc[0][ctl] = __builtin_amdgcn_mfma_f32_16x16x32_f16(bk, aq[0][ks], sacc[0][ctl], 0, 0, 0);
                    sacc[1][ctl] = __builtin_amdgcn_mfma_f32_16x16x32_f16(bk, aq[1][ks], sacc[1][ctl], 0, 0, 0);
                }

            // cls column (k==0): chunk 0, sub 0 (ct=0), owner quad 0, reg sacc[q2][0][0]
            if (c0 == 0 && sub == 0 && quad == 0) {
#pragma unroll
                for (int q2 = 0; q2 < 2; ++q2) {
                    int gi = q0row + q2 * 64 + wid * 16 + l16;
                    sacc[q2][0][0] = col0[c0base + (gi < Nn ? gi : 0)];
                }
            }
            // cls row (q==0): q-tile 0, half 0, wave 0, lanes l16==0 (all quads)
            if (q0row == 0 && wid == 0 && l16 == 0) {
#pragma unroll
                for (int ctl = 0; ctl < 4; ++ctl)
#pragma unroll
                    for (int r = 0; r < 4; ++r)
                        sacc[0][ctl][r] = row0[c0base + c0 + (sub * 4 + ctl) * 16 + quad * 4 + r];
            }

            // softmax in-register + PV: one bv (b64) feeds both halves' MFMA16
#pragma unroll
            for (int ctl = 0; ctl < 4; ++ctl) {
                int ct = sub * 4 + ctl;
                float p00 = fast_exp2(sacc[0][ctl][0]);
                float p01 = fast_exp2(sacc[0][ctl][1]);
                float p02 = fast_exp2(sacc[0][ctl][2]);
                float p03 = fast_exp2(sacc[0][ctl][3]);
                lsum[0] += (p00 + p01) + (p02 + p03);
                union { f16x4 v; unsigned int u[2]; } pa0;
                pa0.u[0] = pack2(p00, p01);
                pa0.u[1] = pack2(p02, p03);
                float p10 = fast_exp2(sacc[1][ctl][0]);
                float p11 = fast_exp2(sacc[1][ctl][1]);
                float p12 = fast_exp2(sacc[1][ctl][2]);
                float p13 = fast_exp2(sacc[1][ctl][3]);
                lsum[1] += (p10 + p11) + (p12 + p13);
                union { f16x4 v; unsigned int u[2]; } pa1;
                pa1.u[0] = pack2(p10, p11);
                pa1.u[1] = pack2(p12, p13);
#pragma unroll
                for (int cd = 0; cd < 4; ++cd) {
                    f16x4 bv = *(const f16x4*)&Vt[cd * 16 + l16][ct * 16 + quad * 4];
                    oacc[0][cd] = MFMA16(pa0.v, bv, oacc[0][cd]);
                    oacc[1][cd] = MFMA16(pa1.v, bv, oacc[1][cd]);
                }
            }
        }
        __syncthreads();   // Ks/Vt consumed before next chunk's commit
    }

    // full row-sums: reduce quad partials (replicated across quads)
#pragma unroll
    for (int q2 = 0; q2 < 2; ++q2) {
        lsum[q2] += __shfl_xor(lsum[q2], 16);
        lsum[q2] += __shfl_xor(lsum[q2], 32);
    }

    // ---- token 1024: rank-1 contribution, per half ----
    const _Float16* k1 = kg + (size_t)1024 * QKVC;
    f16x8 kk0 = *(const f16x8*)(k1 + quad * 8);
    f16x8 kk1 = *(const f16x8*)(k1 + 32 + quad * 8);
    const _Float16* v1 = qg + 2 * DIMC + (size_t)1024 * QKVC;
    float vv[4];
#pragma unroll
    for (int cd = 0; cd < 4; ++cd) vv[cd] = (float)v1[cd * 16 + l16];

#pragma unroll
    for (int q2 = 0; q2 < 2; ++q2) {
        float part = 0.f;
#pragma unroll
        for (int j = 0; j < 8; ++j)
            part += (float)aq[q2][0][j] * (float)kk0[j] + (float)aq[q2][1][j] * (float)kk1[j];
        part += __shfl_xor(part, 16);
        part += __shfl_xor(part, 32);   // s' for row q2*64 + wid*16 + l16 (replicated)
        float s = part;
        if (q0row == 0 && q2 == 0 && wid == 0 && l16 == 0) s = row0[c0base + 1024];  // cls row
        float p = fast_exp2(s);
        lsum[q2] += p;   // own row's contribution (replicated over quads)
        // O rank-1 update: p_r for row ..+quad*4+r lives in lane (quad*4 + r)
#pragma unroll
        for (int r = 0; r < 4; ++r) {
            float pr = __shfl(p, quad * 4 + r);
#pragma unroll
            for (int cd = 0; cd < 4; ++cd) oacc[q2][cd][r] += pr * vv[cd];
        }

        // store: l for row quad*4+r lives (replicated) at lane quad*4+r
#pragma unroll
        for (int r = 0; r < 4; ++r) {
            int gi = q0row + q2 * 64 + wid * 16 + quad * 4 + r;
            if (gi >= Nn) continue;
            float inv_l = 1.0f / __shfl(lsum[q2], quad * 4 + r);
#pragma unroll
            for (int cd = 0; cd < 4; ++cd) {
                att[((size_t)b * Nn + gi) * DIMC + h * HD + cd * 16 + l16] =
                    (_Float16)(oacc[q2][cd][r] * inv_l);
            }
        }
    }
}

extern "C" void kernel_launch(void* const* d_in, const int* in_sizes, int n_in,
                              void* d_out, int out_size, void* d_ws, size_t ws_size,
                              hipStream_t stream) {
    const float* x      = (const float*)d_in[1];
    const int*   xpos   = (const int*)d_in[2];
    const float* w_qkv  = (const float*)d_in[4];
    const float* w_proj = (const float*)d_in[5];
    const float* b_proj = (const float*)d_in[6];
    float* out = (float*)d_out;

    char* ws = (char*)d_ws;
    size_t off = 0;
    auto alloc = [&](size_t bytes) {
        char* p = ws + off;
        off += (bytes + 255) & ~(size_t)255;
        return p;
    };
    _Float16* xh     = (_Float16*)alloc((size_t)MPADA * DIMC * 2);   // padded rows for unguarded staging
    _Float16* qkvh   = (_Float16*)alloc((size_t)MROWS * QKVC * 2);
    _Float16* vt     = (_Float16*)alloc((size_t)Bb * Hh * HD * VNP * 2);
    _Float16* wqkvh  = (_Float16*)alloc((size_t)3 * DIMC * DIMC * 2);
    _Float16* wprojh = (_Float16*)alloc((size_t)DIMC * DIMC * 2);
    float* col0      = (float*)alloc((size_t)Bb * Hh * Nn * 4);
    float* row0      = (float*)alloc((size_t)Bb * Hh * Nn * 4);
    float2* trigtab  = (float2*)alloc((size_t)512 * sizeof(float2));
    _Float16* atth   = xh;  // alias: x consumed by QKV GEMM before flash writes att

    {
        int n0 = (MROWS * DIMC) / 4;
        int n1 = (3 * DIMC * DIMC) / 4;
        int n2 = (DIMC * DIMC) / 4;
        int nt = n0 + n1 + n2 + 512;   // +512 table-builder threads
        cvt3_kernel<<<(nt + 255) / 256, 256, 0, stream>>>(
            x, xh, n0, w_qkv, wqkvh, n1, w_proj, wprojh, n2, trigtab);
    }

    // QKV projection -> packed [b,n,3,h,d] (natural GEMM C layout)
    gemm_kernel<0><<<dim3(MPADA / 128, QKVC / 128), 256, 0, stream>>>(
        xh, wqkvh, MROWS, QKVC, DIMC, qkvh, nullptr, nullptr);

    // fused rope (q/k) + V transpose (tokens 0..1023)
    ropevtrans_kernel<<<RBLK + VTBLK, 256, 0, stream>>>(
        qkvh, xpos, col0, row0, vt, trigtab);

    // XCD-swizzled 1-D grid: 9*96 = 864 blocks
    flash_kernel<<<QT128 * BHTOT, 256, 0, stream>>>(
        qkvh, vt, col0, row0, atth);

    gemm_kernel<1><<<dim3(MPADA / 128, DIMC / 128), 256, 0, stream>>>(
        atth, wprojh, MROWS, DIMC, DIMC, nullptr, b_proj, out);
}